// Round 2
// baseline (1021.350 us; speedup 1.0000x reference)
//
#include <hip/hip_runtime.h>

#define NNODES 100000
#define NEDGES 600000
#define NCLASS 26
#define HID    128

// ---------------- degree / norm ----------------

__global__ void deg_init_k(float* __restrict__ deg, int n) {
    int i = blockIdx.x * 256 + threadIdx.x;
    if (i < n) deg[i] = 1.0f;  // self-loop weight
}

__global__ void deg_acc_k(const int* __restrict__ col, const float* __restrict__ w,
                          float* __restrict__ deg, int E) {
    int e = blockIdx.x * 256 + threadIdx.x;
    if (e < E) atomicAdd(&deg[col[e]], w[e]);
}

__global__ void dinv_k(const float* __restrict__ deg, float* __restrict__ dis, int n) {
    int i = blockIdx.x * 256 + threadIdx.x;
    if (i < n) {
        float d = deg[i];
        dis[i] = d > 0.f ? rsqrtf(fmaxf(d, 1e-12f)) : 0.f;
    }
}

__global__ void norm_k(const int* __restrict__ row, const int* __restrict__ col,
                       const float* __restrict__ w, const float* __restrict__ dis,
                       float* __restrict__ nrm, int E) {
    int e = blockIdx.x * 256 + threadIdx.x;
    if (e < E) nrm[e] = dis[row[e]] * w[e] * dis[col[e]];
}

// ---------------- dense GEMM: C[N,H] = A[N,K] @ W[K,H] (+bias, +relu) ----------------
// W staged in LDS in KC-chunks; BR rows of A staged (padded K+1 to avoid bank
// conflicts when H is not a multiple of the wave width, e.g. H=26).

template <int K, int H, int BR, int KC>
__global__ void gemm_k(const float* __restrict__ A, const float* __restrict__ W,
                       const float* __restrict__ bias, float* __restrict__ C,
                       int N, int applyRelu) {
    constexpr int NT  = 256;
    constexpr int KP  = K + 1;
    constexpr int EPT = (BR * H + NT - 1) / NT;
    __shared__ float Ws[KC * H];
    __shared__ float As[BR * KP];

    const int tid  = threadIdx.x;
    const int row0 = blockIdx.x * BR;
    if (row0 >= N) return;
    const int nrows = min(BR, N - row0);

    // stage A tile (contiguous in global, padded in LDS)
    for (int i = tid; i < nrows * K; i += NT) {
        int r = i / K, k = i % K;
        As[r * KP + k] = A[(size_t)row0 * K + i];
    }

    float acc[EPT];
#pragma unroll
    for (int i = 0; i < EPT; i++) acc[i] = 0.f;

    for (int k0 = 0; k0 < K; k0 += KC) {
        const int kc = min(KC, K - k0);
        __syncthreads();  // As ready (iter 0) / Ws reuse done (iter >0)
        for (int i = tid; i < kc * H; i += NT) Ws[i] = W[k0 * H + i];
        __syncthreads();
#pragma unroll
        for (int i = 0; i < EPT; i++) {
            int idx = tid + i * NT;
            if (idx < nrows * H) {
                int r = idx / H, f = idx % H;
                float a = acc[i];
                const float* as = &As[r * KP + k0];
                const float* ws = &Ws[f];
                for (int k = 0; k < kc; k++) a = fmaf(as[k], ws[k * H], a);
                acc[i] = a;
            }
        }
    }

#pragma unroll
    for (int i = 0; i < EPT; i++) {
        int idx = tid + i * NT;
        if (idx < nrows * H) {
            int r = idx / H, f = idx % H;
            float v = acc[i] + (bias ? bias[f] : 0.f);
            if (applyRelu) v = fmaxf(v, 0.f);
            C[(size_t)(row0 + r) * H + f] = v;
        }
    }
}

// ---------------- self-loop init: out[i,f] = dinv[i]^2 * h[i,f] ----------------

__global__ void selfinit_k(const float* __restrict__ dis, const float* __restrict__ h,
                           float* __restrict__ out, int total) {
    int idx = blockIdx.x * 256 + threadIdx.x;
    if (idx < total) {
        int i = idx >> 7;  // HID == 128
        float d = dis[i];
        out[idx] = d * d * h[idx];
    }
}

// ---------------- edge scatter: out[col,f] += norm[e] * h[row,f] ----------------

__global__ void scatter_k(const int* __restrict__ rows, const int* __restrict__ cols,
                          const float* __restrict__ nrm, const float* __restrict__ h,
                          float* __restrict__ out, int E) {
    long long idx = (long long)blockIdx.x * 256 + threadIdx.x;
    int e = (int)(idx >> 7);
    if (e >= E) return;
    int f = (int)(idx & 127);
    int r = rows[e];
    int c = cols[e];
    atomicAdd(&out[c * HID + f], nrm[e] * h[r * HID + f]);
}

// ---------------- bias + relu in place ----------------

__global__ void bias_relu_k(float* __restrict__ buf, const float* __restrict__ b, int total) {
    int idx = blockIdx.x * 256 + threadIdx.x;
    if (idx < total) {
        int f = idx & 127;
        buf[idx] = fmaxf(buf[idx] + b[f], 0.f);
    }
}

extern "C" void kernel_launch(void* const* d_in, const int* in_sizes, int n_in,
                              void* d_out, int out_size, void* d_ws, size_t ws_size,
                              hipStream_t stream) {
    const float* x   = (const float*)d_in[0];
    const int*   ei  = (const int*)d_in[1];   // [2, E] row-major: row then col
    const float* ew  = (const float*)d_in[2];
    const float* W1  = (const float*)d_in[3];
    const float* b1  = (const float*)d_in[4];
    const float* W2  = (const float*)d_in[5];
    const float* b2  = (const float*)d_in[6];
    const float* Wfc = (const float*)d_in[7];
    const float* bfc = (const float*)d_in[8];
    float* out = (float*)d_out;

    const int N = NNODES, E = NEDGES;
    const int* erow = ei;
    const int* ecol = ei + E;

    // workspace layout (floats): deg[N] dis[N] nrm[E] bufA[N*128] bufB[N*128]
    float* deg  = (float*)d_ws;
    float* dis  = deg + N;
    float* nrm  = dis + N;
    float* bufA = nrm + E;
    float* bufB = bufA + (size_t)N * HID;

    const int gN  = (N + 255) / 256;
    const int gE  = (E + 255) / 256;
    const int NF  = N * HID;                 // 12.8M
    const int gNF = (NF + 255) / 256;
    const long long EF = (long long)E * HID; // 76.8M
    const int gEF = (int)((EF + 255) / 256);
    const int gGe = (N + 15) / 16;           // gemm blocks, BR=16

    // ---- gcn_norm ----
    deg_init_k<<<gN, 256, 0, stream>>>(deg, N);
    deg_acc_k<<<gE, 256, 0, stream>>>(ecol, ew, deg, E);
    dinv_k<<<gN, 256, 0, stream>>>(deg, dis, N);
    norm_k<<<gE, 256, 0, stream>>>(erow, ecol, ew, dis, nrm, E);

    // ---- layer 1: x@W1 -> scatter -> +b1, relu ----
    gemm_k<NCLASS, HID, 16, NCLASS><<<gGe, 256, 0, stream>>>(x, W1, nullptr, bufA, N, 0);
    selfinit_k<<<gNF, 256, 0, stream>>>(dis, bufA, bufB, NF);
    scatter_k<<<gEF, 256, 0, stream>>>(erow, ecol, nrm, bufA, bufB, E);
    bias_relu_k<<<gNF, 256, 0, stream>>>(bufB, b1, NF);

    // ---- layer 2: h@W2 -> scatter -> +b2, relu ----
    gemm_k<HID, HID, 16, 64><<<gGe, 256, 0, stream>>>(bufB, W2, nullptr, bufA, N, 0);
    selfinit_k<<<gNF, 256, 0, stream>>>(dis, bufA, bufB, NF);
    scatter_k<<<gEF, 256, 0, stream>>>(erow, ecol, nrm, bufA, bufB, E);
    bias_relu_k<<<gNF, 256, 0, stream>>>(bufB, b2, NF);

    // ---- fc: h@Wfc + bfc ----
    gemm_k<HID, NCLASS, 16, HID><<<gGe, 256, 0, stream>>>(bufB, Wfc, bfc, out, N, 0);
}

// Round 3
// 473.197 us; speedup vs baseline: 2.1584x; 2.1584x over previous
//
#include <hip/hip_runtime.h>

#define NNODES 100000
#define NEDGES 600000
#define NCLASS 26
#define HID    128
#define NBLK   391   // ceil(NNODES/256)

// ---------------- init: dis=1 (self-loop weight), cnt=0 ----------------
__global__ void init_k(float* __restrict__ dis, int* __restrict__ cnt, int n) {
    int i = blockIdx.x * 256 + threadIdx.x;
    if (i < n) { dis[i] = 1.0f; cnt[i] = 0; }
}

// ---------------- fused degree-accumulate + in-degree histogram ----------------
__global__ void degcnt_k(const int* __restrict__ col, const float* __restrict__ w,
                         float* __restrict__ deg, int* __restrict__ cnt, int E) {
    int e = blockIdx.x * 256 + threadIdx.x;
    if (e < E) {
        int c = col[e];
        atomicAdd(&deg[c], w[e]);
        atomicAdd(&cnt[c], 1);
    }
}

__global__ void dinv_k(float* __restrict__ dis, int n) {
    int i = blockIdx.x * 256 + threadIdx.x;
    if (i < n) {
        float d = dis[i];
        dis[i] = d > 0.f ? rsqrtf(fmaxf(d, 1e-12f)) : 0.f;
    }
}

// ---------------- block-wise inclusive scan of cnt -> rowptr, block sums -> aux ----
__global__ void scan1_k(const int* __restrict__ cnt, int* __restrict__ incl,
                        int* __restrict__ aux, int n) {
    __shared__ int s[256];
    int t = threadIdx.x, gi = blockIdx.x * 256 + t;
    s[t] = (gi < n) ? cnt[gi] : 0;
    __syncthreads();
    for (int off = 1; off < 256; off <<= 1) {
        int x = (t >= off) ? s[t - off] : 0;
        __syncthreads();
        s[t] += x;
        __syncthreads();
    }
    if (gi < n) incl[gi] = s[t];
    if (t == 255) aux[blockIdx.x] = s[255];
}

__global__ void scan2_k(int* __restrict__ aux, int n) {  // single block, 512 thr
    __shared__ int s[512];
    int t = threadIdx.x;
    s[t] = (t < n) ? aux[t] : 0;
    __syncthreads();
    for (int off = 1; off < 512; off <<= 1) {
        int x = (t >= off) ? s[t - off] : 0;
        __syncthreads();
        s[t] += x;
        __syncthreads();
    }
    if (t < n) aux[t] = s[t];
}

// incl -> exclusive global rowptr; zero cnt (becomes placement cursor)
__global__ void scan3_k(int* __restrict__ rowptr, int* __restrict__ cnt,
                        const int* __restrict__ aux, int n) {
    int gi = blockIdx.x * 256 + threadIdx.x;
    if (gi < n) {
        int add = (blockIdx.x > 0) ? aux[blockIdx.x - 1] : 0;
        rowptr[gi] = rowptr[gi] - cnt[gi] + add;
        cnt[gi] = 0;
    }
    if (gi == 0) rowptr[n] = NEDGES;
}

// ---------------- place edges into CSR (by destination), val = full norm ----------
__global__ void place_k(const int* __restrict__ row, const int* __restrict__ col,
                        const float* __restrict__ w, const float* __restrict__ dis,
                        const int* __restrict__ rowptr, int* __restrict__ cursor,
                        int* __restrict__ src, float* __restrict__ val, int E) {
    int e = blockIdx.x * 256 + threadIdx.x;
    if (e < E) {
        int r = row[e], c = col[e];
        int pos = rowptr[c] + atomicAdd(&cursor[c], 1);
        src[pos] = r;
        val[pos] = dis[r] * w[e] * dis[c];
    }
}

// ---------------- gather-aggregate + self-loop + bias + relu -----------------------
// one wave per node; lane handles 2 feats via float2 (h rows are 512B, coalesced)
__global__ __launch_bounds__(256) void agg_k(const int* __restrict__ rowptr,
                                             const int* __restrict__ src,
                                             const float* __restrict__ val,
                                             const float* __restrict__ h,
                                             const float* __restrict__ dis,
                                             const float* __restrict__ bias,
                                             float* __restrict__ out) {
    int node = blockIdx.x * 4 + (threadIdx.x >> 6);
    if (node >= NNODES) return;
    int lane = threadIdx.x & 63;
    const float2* h2 = (const float2*)h;

    float d = dis[node];
    float2 hc = h2[node * 64 + lane];
    float2 acc;
    acc.x = d * d * hc.x;
    acc.y = d * d * hc.y;

    int j = rowptr[node], jend = rowptr[node + 1];
    for (; j + 1 < jend; j += 2) {  // 2-way unroll: two gathers in flight
        int   r0 = src[j],     r1 = src[j + 1];
        float v0 = val[j],     v1 = val[j + 1];
        float2 a = h2[r0 * 64 + lane];
        float2 b = h2[r1 * 64 + lane];
        acc.x = fmaf(v0, a.x, acc.x); acc.y = fmaf(v0, a.y, acc.y);
        acc.x = fmaf(v1, b.x, acc.x); acc.y = fmaf(v1, b.y, acc.y);
    }
    if (j < jend) {
        int r = src[j]; float v = val[j];
        float2 a = h2[r * 64 + lane];
        acc.x = fmaf(v, a.x, acc.x); acc.y = fmaf(v, a.y, acc.y);
    }

    float2 b2v = ((const float2*)bias)[lane];
    acc.x = fmaxf(acc.x + b2v.x, 0.f);
    acc.y = fmaxf(acc.y + b2v.y, 0.f);
    ((float2*)out)[node * 64 + lane] = acc;
}

// ---------------- register-tiled GEMM: C[N,128] = A[N,128] @ W[128,128] ------------
// 128x128 block tile, 256 threads, 8x8 micro-tile, A transposed in LDS (pad 132
// keeps float4 alignment and spreads banks), float4 LDS reads.
__global__ __launch_bounds__(256) void gemm128_k(const float* __restrict__ A,
                                                 const float* __restrict__ W,
                                                 float* __restrict__ C, int N) {
    constexpr int AP = 132;
    __shared__ float As[32 * AP];   // As[k][row]
    __shared__ float Ws[32 * 128];  // Ws[k][col]
    const int tid = threadIdx.x;
    const int tx = tid & 15;   // col group -> cols tx*8..+7
    const int ty = tid >> 4;   // row group -> rows ty*8..+7
    const int row0 = blockIdx.x * 128;
    const int nrows = min(128, N - row0);

    float acc[8][8];
#pragma unroll
    for (int i = 0; i < 8; i++)
#pragma unroll
        for (int jj = 0; jj < 8; jj++) acc[i][jj] = 0.f;

    for (int k0 = 0; k0 < 128; k0 += 32) {
        __syncthreads();
        for (int i = tid; i < 128 * 32; i += 256) {
            int r = i >> 5, k = i & 31;
            As[k * AP + r] = (r < nrows) ? A[(size_t)(row0 + r) * 128 + k0 + k] : 0.f;
        }
        for (int i = tid; i < 32 * 128; i += 256) {
            Ws[i] = W[(size_t)(k0 + (i >> 7)) * 128 + (i & 127)];
        }
        __syncthreads();
#pragma unroll 4
        for (int k = 0; k < 32; k++) {
            float4 a0 = *(const float4*)&As[k * AP + ty * 8];
            float4 a1 = *(const float4*)&As[k * AP + ty * 8 + 4];
            float4 w0 = *(const float4*)&Ws[k * 128 + tx * 8];
            float4 w1 = *(const float4*)&Ws[k * 128 + tx * 8 + 4];
            float a[8] = {a0.x, a0.y, a0.z, a0.w, a1.x, a1.y, a1.z, a1.w};
            float w[8] = {w0.x, w0.y, w0.z, w0.w, w1.x, w1.y, w1.z, w1.w};
#pragma unroll
            for (int i = 0; i < 8; i++)
#pragma unroll
                for (int jj = 0; jj < 8; jj++)
                    acc[i][jj] = fmaf(a[i], w[jj], acc[i][jj]);
        }
    }

#pragma unroll
    for (int i = 0; i < 8; i++) {
        int r = ty * 8 + i;
        if (r < nrows) {
            float4 v0 = {acc[i][0], acc[i][1], acc[i][2], acc[i][3]};
            float4 v1 = {acc[i][4], acc[i][5], acc[i][6], acc[i][7]};
            *(float4*)&C[(size_t)(row0 + r) * 128 + tx * 8] = v0;
            *(float4*)&C[(size_t)(row0 + r) * 128 + tx * 8 + 4] = v1;
        }
    }
}

// ---------------- generic small GEMM (kept for K=26 in, H=26 out) ------------------
template <int K, int H, int BR, int KC>
__global__ void gemm_k(const float* __restrict__ A, const float* __restrict__ W,
                       const float* __restrict__ bias, float* __restrict__ C,
                       int N, int applyRelu) {
    constexpr int NT  = 256;
    constexpr int KP  = K + 1;
    constexpr int EPT = (BR * H + NT - 1) / NT;
    __shared__ float Ws[KC * H];
    __shared__ float As[BR * KP];

    const int tid  = threadIdx.x;
    const int row0 = blockIdx.x * BR;
    if (row0 >= N) return;
    const int nrows = min(BR, N - row0);

    for (int i = tid; i < nrows * K; i += NT) {
        int r = i / K, k = i % K;
        As[r * KP + k] = A[(size_t)row0 * K + i];
    }

    float acc[EPT];
#pragma unroll
    for (int i = 0; i < EPT; i++) acc[i] = 0.f;

    for (int k0 = 0; k0 < K; k0 += KC) {
        const int kc = min(KC, K - k0);
        __syncthreads();
        for (int i = tid; i < kc * H; i += NT) Ws[i] = W[k0 * H + i];
        __syncthreads();
#pragma unroll
        for (int i = 0; i < EPT; i++) {
            int idx = tid + i * NT;
            if (idx < nrows * H) {
                int r = idx / H, f = idx % H;
                float a = acc[i];
                const float* as = &As[r * KP + k0];
                const float* ws = &Ws[f];
                for (int k = 0; k < kc; k++) a = fmaf(as[k], ws[k * H], a);
                acc[i] = a;
            }
        }
    }

#pragma unroll
    for (int i = 0; i < EPT; i++) {
        int idx = tid + i * NT;
        if (idx < nrows * H) {
            int r = idx / H, f = idx % H;
            float v = acc[i] + (bias ? bias[f] : 0.f);
            if (applyRelu) v = fmaxf(v, 0.f);
            C[(size_t)(row0 + r) * H + f] = v;
        }
    }
}

extern "C" void kernel_launch(void* const* d_in, const int* in_sizes, int n_in,
                              void* d_out, int out_size, void* d_ws, size_t ws_size,
                              hipStream_t stream) {
    const float* x   = (const float*)d_in[0];
    const int*   ei  = (const int*)d_in[1];   // [2, E]: row then col
    const float* ew  = (const float*)d_in[2];
    const float* W1  = (const float*)d_in[3];
    const float* b1  = (const float*)d_in[4];
    const float* W2  = (const float*)d_in[5];
    const float* b2  = (const float*)d_in[6];
    const float* Wfc = (const float*)d_in[7];
    const float* bfc = (const float*)d_in[8];
    float* out = (float*)d_out;

    const int N = NNODES, E = NEDGES;
    const int* erow = ei;
    const int* ecol = ei + E;

    // ws layout (float units, 16B-aligned sections):
    // dis[100000] cnt[100000] rowptr[100004] aux[512] src[600000] val[600000]
    // bufA[12.8M] bufB[12.8M]   total ~108.4 MB
    float* fws    = (float*)d_ws;
    float* dis    = fws;                       // 0
    int*   cnt    = (int*)(fws + 100000);      // 100000
    int*   rowptr = (int*)(fws + 200000);      // 200000 (100004 incl pad)
    int*   aux    = (int*)(fws + 300004);      // 512
    int*   src    = (int*)(fws + 300516);      // 600000
    float* val    = fws + 900516;              // 600000
    float* bufA   = fws + 1500516;             // 16B aligned
    float* bufB   = fws + 14300516;

    const int gN = (N + 255) / 256;   // 391
    const int gE = (E + 255) / 256;

    // ---- gcn_norm + CSR build ----
    init_k<<<gN, 256, 0, stream>>>(dis, cnt, N);
    degcnt_k<<<gE, 256, 0, stream>>>(ecol, ew, dis, cnt, E);
    dinv_k<<<gN, 256, 0, stream>>>(dis, N);
    scan1_k<<<NBLK, 256, 0, stream>>>(cnt, rowptr, aux, N);
    scan2_k<<<1, 512, 0, stream>>>(aux, NBLK);
    scan3_k<<<NBLK, 256, 0, stream>>>(rowptr, cnt, aux, N);
    place_k<<<gE, 256, 0, stream>>>(erow, ecol, ew, dis, rowptr, cnt, src, val, E);

    // ---- layer 1: x@W1 -> gather-agg(+b1, relu) ----
    gemm_k<NCLASS, HID, 16, NCLASS><<<(N + 15) / 16, 256, 0, stream>>>(x, W1, nullptr, bufA, N, 0);
    agg_k<<<N / 4, 256, 0, stream>>>(rowptr, src, val, bufA, dis, b1, bufB);

    // ---- layer 2: h@W2 -> gather-agg(+b2, relu) ----
    gemm128_k<<<(N + 127) / 128, 256, 0, stream>>>(bufB, W2, bufA, N);
    agg_k<<<N / 4, 256, 0, stream>>>(rowptr, src, val, bufA, dis, b2, bufB);

    // ---- fc ----
    gemm_k<HID, NCLASS, 16, HID><<<(N + 15) / 16, 256, 0, stream>>>(bufB, Wfc, bfc, out, N, 0);
}

// Round 4
// 436.422 us; speedup vs baseline: 2.3403x; 1.0843x over previous
//
#include <hip/hip_runtime.h>

#define NNODES 100000
#define NEDGES 600000
#define NCLASS 26
#define HID    128
#define NBLK   391   // ceil(NNODES/256)

// ---------------- init: dis=1 (self-loop weight), cnt=0 ----------------
__global__ void init_k(float* __restrict__ dis, int* __restrict__ cnt, int n) {
    int i = blockIdx.x * 256 + threadIdx.x;
    if (i < n) { dis[i] = 1.0f; cnt[i] = 0; }
}

// ---------------- fused degree-accumulate + in-degree histogram ----------------
__global__ void degcnt_k(const int* __restrict__ col, const float* __restrict__ w,
                         float* __restrict__ deg, int* __restrict__ cnt, int E) {
    int e = blockIdx.x * 256 + threadIdx.x;
    if (e < E) {
        int c = col[e];
        atomicAdd(&deg[c], w[e]);
        atomicAdd(&cnt[c], 1);
    }
}

__global__ void dinv_k(float* __restrict__ dis, int n) {
    int i = blockIdx.x * 256 + threadIdx.x;
    if (i < n) {
        float d = dis[i];
        dis[i] = d > 0.f ? rsqrtf(fmaxf(d, 1e-12f)) : 0.f;
    }
}

// ---------------- block-wise inclusive scan of cnt -> rowptr, block sums -> aux ----
__global__ void scan1_k(const int* __restrict__ cnt, int* __restrict__ incl,
                        int* __restrict__ aux, int n) {
    __shared__ int s[256];
    int t = threadIdx.x, gi = blockIdx.x * 256 + t;
    s[t] = (gi < n) ? cnt[gi] : 0;
    __syncthreads();
    for (int off = 1; off < 256; off <<= 1) {
        int x = (t >= off) ? s[t - off] : 0;
        __syncthreads();
        s[t] += x;
        __syncthreads();
    }
    if (gi < n) incl[gi] = s[t];
    if (t == 255) aux[blockIdx.x] = s[255];
}

__global__ void scan2_k(int* __restrict__ aux, int n) {  // single block, 512 thr
    __shared__ int s[512];
    int t = threadIdx.x;
    s[t] = (t < n) ? aux[t] : 0;
    __syncthreads();
    for (int off = 1; off < 512; off <<= 1) {
        int x = (t >= off) ? s[t - off] : 0;
        __syncthreads();
        s[t] += x;
        __syncthreads();
    }
    if (t < n) aux[t] = s[t];
}

// incl -> exclusive global rowptr; zero cnt (becomes placement cursor)
__global__ void scan3_k(int* __restrict__ rowptr, int* __restrict__ cnt,
                        const int* __restrict__ aux, int n) {
    int gi = blockIdx.x * 256 + threadIdx.x;
    if (gi < n) {
        int add = (blockIdx.x > 0) ? aux[blockIdx.x - 1] : 0;
        rowptr[gi] = rowptr[gi] - cnt[gi] + add;
        cnt[gi] = 0;
    }
    if (gi == 0) rowptr[n] = NEDGES;
}

// ---------------- place edges into CSR (by destination), val = full norm ----------
__global__ void place_k(const int* __restrict__ row, const int* __restrict__ col,
                        const float* __restrict__ w, const float* __restrict__ dis,
                        const int* __restrict__ rowptr, int* __restrict__ cursor,
                        int* __restrict__ src, float* __restrict__ val, int E) {
    int e = blockIdx.x * 256 + threadIdx.x;
    if (e < E) {
        int r = row[e], c = col[e];
        int pos = rowptr[c] + atomicAdd(&cursor[c], 1);
        src[pos] = r;
        val[pos] = dis[r] * w[e] * dis[c];
    }
}

// ---------------- gather-aggregate + self-loop + bias + relu -----------------------
__global__ __launch_bounds__(256) void agg_k(const int* __restrict__ rowptr,
                                             const int* __restrict__ src,
                                             const float* __restrict__ val,
                                             const float* __restrict__ h,
                                             const float* __restrict__ dis,
                                             const float* __restrict__ bias,
                                             float* __restrict__ out) {
    int node = blockIdx.x * 4 + (threadIdx.x >> 6);
    if (node >= NNODES) return;
    int lane = threadIdx.x & 63;
    const float2* h2 = (const float2*)h;

    float d = dis[node];
    float2 hc = h2[node * 64 + lane];
    float2 acc;
    acc.x = d * d * hc.x;
    acc.y = d * d * hc.y;

    int j = rowptr[node], jend = rowptr[node + 1];
    for (; j + 1 < jend; j += 2) {
        int   r0 = src[j],     r1 = src[j + 1];
        float v0 = val[j],     v1 = val[j + 1];
        float2 a = h2[r0 * 64 + lane];
        float2 b = h2[r1 * 64 + lane];
        acc.x = fmaf(v0, a.x, acc.x); acc.y = fmaf(v0, a.y, acc.y);
        acc.x = fmaf(v1, b.x, acc.x); acc.y = fmaf(v1, b.y, acc.y);
    }
    if (j < jend) {
        int r = src[j]; float v = val[j];
        float2 a = h2[r * 64 + lane];
        acc.x = fmaf(v, a.x, acc.x); acc.y = fmaf(v, a.y, acc.y);
    }

    float2 b2v = ((const float2*)bias)[lane];
    acc.x = fmaxf(acc.x + b2v.x, 0.f);
    acc.y = fmaxf(acc.y + b2v.y, 0.f);
    ((float2*)out)[node * 64 + lane] = acc;
}

// ---------------- GEMM 128x128: C[N,128] = A[N,128] @ W[128,128] -------------------
// 8x8 microtile. Within-wave cg,rg each span 0..7 (wave id supplies bit 3), so
// float4 LDS reads hit 8 distinct addresses per 4-bank group = 2-way = free (m136).
__global__ __launch_bounds__(256) void gemm128_k(const float* __restrict__ A,
                                                 const float* __restrict__ W,
                                                 float* __restrict__ C, int N) {
    constexpr int AP = 132;
    __shared__ float As[32 * AP];   // As[k][row]
    __shared__ float Ws[32 * 128];  // Ws[k][col]
    const int tid  = threadIdx.x;
    const int wave = tid >> 6, lane = tid & 63;
    const int cg = (lane & 7) | ((wave & 1) << 3);          // 0..15 col group
    const int rg = ((lane >> 3) & 7) | ((wave >> 1) << 3);  // 0..15 row group
    const int row0 = blockIdx.x * 128;
    const int nrows = min(128, N - row0);

    float acc[8][8];
#pragma unroll
    for (int i = 0; i < 8; i++)
#pragma unroll
        for (int jj = 0; jj < 8; jj++) acc[i][jj] = 0.f;

    for (int k0 = 0; k0 < 128; k0 += 32) {
        __syncthreads();
        for (int i = tid; i < 128 * 32; i += 256) {
            int r = i >> 5, k = i & 31;
            As[k * AP + r] = (r < nrows) ? A[(size_t)(row0 + r) * 128 + k0 + k] : 0.f;
        }
        for (int i = tid; i < 32 * 128; i += 256) {
            Ws[i] = W[(size_t)(k0 + (i >> 7)) * 128 + (i & 127)];
        }
        __syncthreads();
#pragma unroll 4
        for (int k = 0; k < 32; k++) {
            float4 a0 = *(const float4*)&As[k * AP + rg * 8];
            float4 a1 = *(const float4*)&As[k * AP + rg * 8 + 4];
            float4 w0 = *(const float4*)&Ws[k * 128 + cg * 8];
            float4 w1 = *(const float4*)&Ws[k * 128 + cg * 8 + 4];
            float a[8] = {a0.x, a0.y, a0.z, a0.w, a1.x, a1.y, a1.z, a1.w};
            float w[8] = {w0.x, w0.y, w0.z, w0.w, w1.x, w1.y, w1.z, w1.w};
#pragma unroll
            for (int i = 0; i < 8; i++)
#pragma unroll
                for (int jj = 0; jj < 8; jj++)
                    acc[i][jj] = fmaf(a[i], w[jj], acc[i][jj]);
        }
    }

#pragma unroll
    for (int i = 0; i < 8; i++) {
        int r = rg * 8 + i;
        if (r < nrows) {
            float4 v0 = {acc[i][0], acc[i][1], acc[i][2], acc[i][3]};
            float4 v1 = {acc[i][4], acc[i][5], acc[i][6], acc[i][7]};
            *(float4*)&C[(size_t)(row0 + r) * 128 + cg * 8] = v0;
            *(float4*)&C[(size_t)(row0 + r) * 128 + cg * 8 + 4] = v1;
        }
    }
}

// ---------------- GEMM K=26: C[N,128] = A[N,26] @ W1[26,128] -----------------------
// Same 8x8 microtile / conflict-free mapping; single K chunk (K=26).
__global__ __launch_bounds__(256) void gemm1_k(const float* __restrict__ A,
                                               const float* __restrict__ W,
                                               float* __restrict__ C, int N) {
    constexpr int AP = 132;
    __shared__ float As[26 * AP];
    __shared__ float Ws[26 * 128];
    const int tid  = threadIdx.x;
    const int wave = tid >> 6, lane = tid & 63;
    const int cg = (lane & 7) | ((wave & 1) << 3);
    const int rg = ((lane >> 3) & 7) | ((wave >> 1) << 3);
    const int row0 = blockIdx.x * 128;
    const int nrows = min(128, N - row0);

    for (int i = tid; i < 128 * 26; i += 256) {
        int r = i / 26, k = i - r * 26;
        As[k * AP + r] = (r < nrows) ? A[(size_t)row0 * 26 + i] : 0.f;
    }
    for (int i = tid; i < 26 * 128; i += 256) Ws[i] = W[i];

    float acc[8][8];
#pragma unroll
    for (int i = 0; i < 8; i++)
#pragma unroll
        for (int jj = 0; jj < 8; jj++) acc[i][jj] = 0.f;

    __syncthreads();
#pragma unroll 2
    for (int k = 0; k < 26; k++) {
        float4 a0 = *(const float4*)&As[k * AP + rg * 8];
        float4 a1 = *(const float4*)&As[k * AP + rg * 8 + 4];
        float4 w0 = *(const float4*)&Ws[k * 128 + cg * 8];
        float4 w1 = *(const float4*)&Ws[k * 128 + cg * 8 + 4];
        float a[8] = {a0.x, a0.y, a0.z, a0.w, a1.x, a1.y, a1.z, a1.w};
        float w[8] = {w0.x, w0.y, w0.z, w0.w, w1.x, w1.y, w1.z, w1.w};
#pragma unroll
        for (int i = 0; i < 8; i++)
#pragma unroll
            for (int jj = 0; jj < 8; jj++)
                acc[i][jj] = fmaf(a[i], w[jj], acc[i][jj]);
    }

#pragma unroll
    for (int i = 0; i < 8; i++) {
        int r = rg * 8 + i;
        if (r < nrows) {
            float4 v0 = {acc[i][0], acc[i][1], acc[i][2], acc[i][3]};
            float4 v1 = {acc[i][4], acc[i][5], acc[i][6], acc[i][7]};
            *(float4*)&C[(size_t)(row0 + r) * 128 + cg * 8] = v0;
            *(float4*)&C[(size_t)(row0 + r) * 128 + cg * 8 + 4] = v1;
        }
    }
}

// ---------------- fc: C[N,26] = A[N,128] @ Wfc[128,26] + bfc -----------------------
// Cols padded to 32 in LDS; 4x4 microtile: within-wave cg,rg span 0..7 ->
// float4 reads cover all 32 banks exactly once = conflict-free.
__global__ __launch_bounds__(256) void gemmfc_k(const float* __restrict__ A,
                                                const float* __restrict__ W,
                                                const float* __restrict__ bias,
                                                float* __restrict__ C, int N) {
    constexpr int AP = 132;
    __shared__ float As[32 * AP];
    __shared__ float Ws[32 * 32];
    __shared__ float bs[32];
    const int tid  = threadIdx.x;
    const int wave = tid >> 6, lane = tid & 63;
    const int cg = lane & 7;                     // 0..7 -> cols cg*4..+3 (of 32)
    const int rg = ((lane >> 3) & 7) | (wave << 3);  // 0..31 -> rows rg*4..+3
    const int row0 = blockIdx.x * 128;
    const int nrows = min(128, N - row0);

    if (tid < 32) bs[tid] = (tid < NCLASS) ? bias[tid] : 0.f;

    float acc[4][4];
#pragma unroll
    for (int i = 0; i < 4; i++)
#pragma unroll
        for (int jj = 0; jj < 4; jj++) acc[i][jj] = 0.f;

    for (int k0 = 0; k0 < 128; k0 += 32) {
        __syncthreads();
        for (int i = tid; i < 128 * 32; i += 256) {
            int r = i >> 5, k = i & 31;
            As[k * AP + r] = (r < nrows) ? A[(size_t)(row0 + r) * 128 + k0 + k] : 0.f;
        }
        for (int i = tid; i < 32 * 32; i += 256) {
            int k = i >> 5, c = i & 31;
            Ws[i] = (c < NCLASS) ? W[(size_t)(k0 + k) * NCLASS + c] : 0.f;
        }
        __syncthreads();
#pragma unroll 4
        for (int k = 0; k < 32; k++) {
            float4 a0 = *(const float4*)&As[k * AP + rg * 4];
            float4 w0 = *(const float4*)&Ws[k * 32 + cg * 4];
            float a[4] = {a0.x, a0.y, a0.z, a0.w};
            float w[4] = {w0.x, w0.y, w0.z, w0.w};
#pragma unroll
            for (int i = 0; i < 4; i++)
#pragma unroll
                for (int jj = 0; jj < 4; jj++)
                    acc[i][jj] = fmaf(a[i], w[jj], acc[i][jj]);
        }
    }

    const int c0 = cg * 4;
#pragma unroll
    for (int i = 0; i < 4; i++) {
        int r = rg * 4 + i;
        if (r < nrows && c0 < NCLASS) {
            float* dst = &C[(size_t)(row0 + r) * NCLASS + c0];
            if (c0 + 3 < NCLASS) {  // cols 0..23: full float4
                float4 v = {acc[i][0] + bs[c0], acc[i][1] + bs[c0 + 1],
                            acc[i][2] + bs[c0 + 2], acc[i][3] + bs[c0 + 3]};
                *(float4*)dst = v;
            } else {                // cols 24..25
                dst[0] = acc[i][0] + bs[c0];
                dst[1] = acc[i][1] + bs[c0 + 1];
            }
        }
    }
}

extern "C" void kernel_launch(void* const* d_in, const int* in_sizes, int n_in,
                              void* d_out, int out_size, void* d_ws, size_t ws_size,
                              hipStream_t stream) {
    const float* x   = (const float*)d_in[0];
    const int*   ei  = (const int*)d_in[1];   // [2, E]: row then col
    const float* ew  = (const float*)d_in[2];
    const float* W1  = (const float*)d_in[3];
    const float* b1  = (const float*)d_in[4];
    const float* W2  = (const float*)d_in[5];
    const float* b2  = (const float*)d_in[6];
    const float* Wfc = (const float*)d_in[7];
    const float* bfc = (const float*)d_in[8];
    float* out = (float*)d_out;

    const int N = NNODES, E = NEDGES;
    const int* erow = ei;
    const int* ecol = ei + E;

    // ws layout (float units):
    // dis[100000] cnt[100000] rowptr[100004] aux[512] src[600000] val[600000]
    // bufA[12.8M] bufB[12.8M]   total ~108.4 MB
    float* fws    = (float*)d_ws;
    float* dis    = fws;
    int*   cnt    = (int*)(fws + 100000);
    int*   rowptr = (int*)(fws + 200000);
    int*   aux    = (int*)(fws + 300004);
    int*   src    = (int*)(fws + 300516);
    float* val    = fws + 900516;
    float* bufA   = fws + 1500516;
    float* bufB   = fws + 14300516;

    const int gN = (N + 255) / 256;   // 391
    const int gE = (E + 255) / 256;
    const int g128 = (N + 127) / 128; // 782

    // ---- gcn_norm + CSR build ----
    init_k<<<gN, 256, 0, stream>>>(dis, cnt, N);
    degcnt_k<<<gE, 256, 0, stream>>>(ecol, ew, dis, cnt, E);
    dinv_k<<<gN, 256, 0, stream>>>(dis, N);
    scan1_k<<<NBLK, 256, 0, stream>>>(cnt, rowptr, aux, N);
    scan2_k<<<1, 512, 0, stream>>>(aux, NBLK);
    scan3_k<<<NBLK, 256, 0, stream>>>(rowptr, cnt, aux, N);
    place_k<<<gE, 256, 0, stream>>>(erow, ecol, ew, dis, rowptr, cnt, src, val, E);

    // ---- layer 1: x@W1 -> gather-agg(+b1, relu) ----
    gemm1_k<<<g128, 256, 0, stream>>>(x, W1, bufA, N);
    agg_k<<<N / 4, 256, 0, stream>>>(rowptr, src, val, bufA, dis, b1, bufB);

    // ---- layer 2: h@W2 -> gather-agg(+b2, relu) ----
    gemm128_k<<<g128, 256, 0, stream>>>(bufB, W2, bufA, N);
    agg_k<<<N / 4, 256, 0, stream>>>(rowptr, src, val, bufA, dis, b2, bufB);

    // ---- fc ----
    gemmfc_k<<<g128, 256, 0, stream>>>(bufB, Wfc, bfc, out, N);
}

// Round 5
// 352.968 us; speedup vs baseline: 2.8936x; 1.2364x over previous
//
#include <hip/hip_runtime.h>

#define NNODES 100000
#define NEDGES 600000
#define NCLASS 26
#define HID    128
#define NBLK   391   // ceil(NNODES/256)

typedef __attribute__((ext_vector_type(8))) short bf16x8;  // 8 bf16 = 4 VGPRs
typedef __attribute__((ext_vector_type(4))) float f32x4;

__device__ inline unsigned short f2bf(float f) {  // RNE fp32->bf16
    unsigned int u = __float_as_uint(f);
    u += 0x7fffu + ((u >> 16) & 1u);
    return (unsigned short)(u >> 16);
}
__device__ inline float bf2f(unsigned short b) {
    return __uint_as_float((unsigned int)b << 16);
}
__device__ inline unsigned int packbf(float a, float b) {
    return (unsigned int)f2bf(a) | ((unsigned int)f2bf(b) << 16);
}
__device__ inline float2 bfpair(unsigned int p) {  // lo ushort = first feat
    float2 r;
    r.x = __uint_as_float(p << 16);
    r.y = __uint_as_float(p & 0xffff0000u);
    return r;
}

// ---------------- init: dis=1 (self-loop weight), cnt=0 ----------------
__global__ void init_k(float* __restrict__ dis, int* __restrict__ cnt, int n) {
    int i = blockIdx.x * 256 + threadIdx.x;
    if (i < n) { dis[i] = 1.0f; cnt[i] = 0; }
}

__global__ void degcnt_k(const int* __restrict__ col, const float* __restrict__ w,
                         float* __restrict__ deg, int* __restrict__ cnt, int E) {
    int e = blockIdx.x * 256 + threadIdx.x;
    if (e < E) {
        int c = col[e];
        atomicAdd(&deg[c], w[e]);
        atomicAdd(&cnt[c], 1);
    }
}

__global__ void dinv_k(float* __restrict__ dis, int n) {
    int i = blockIdx.x * 256 + threadIdx.x;
    if (i < n) {
        float d = dis[i];
        dis[i] = d > 0.f ? rsqrtf(fmaxf(d, 1e-12f)) : 0.f;
    }
}

__global__ void scan1_k(const int* __restrict__ cnt, int* __restrict__ incl,
                        int* __restrict__ aux, int n) {
    __shared__ int s[256];
    int t = threadIdx.x, gi = blockIdx.x * 256 + t;
    s[t] = (gi < n) ? cnt[gi] : 0;
    __syncthreads();
    for (int off = 1; off < 256; off <<= 1) {
        int x = (t >= off) ? s[t - off] : 0;
        __syncthreads();
        s[t] += x;
        __syncthreads();
    }
    if (gi < n) incl[gi] = s[t];
    if (t == 255) aux[blockIdx.x] = s[255];
}

__global__ void scan2_k(int* __restrict__ aux, int n) {
    __shared__ int s[512];
    int t = threadIdx.x;
    s[t] = (t < n) ? aux[t] : 0;
    __syncthreads();
    for (int off = 1; off < 512; off <<= 1) {
        int x = (t >= off) ? s[t - off] : 0;
        __syncthreads();
        s[t] += x;
        __syncthreads();
    }
    if (t < n) aux[t] = s[t];
}

__global__ void scan3_k(int* __restrict__ rowptr, int* __restrict__ cnt,
                        const int* __restrict__ aux, int n) {
    int gi = blockIdx.x * 256 + threadIdx.x;
    if (gi < n) {
        int add = (blockIdx.x > 0) ? aux[blockIdx.x - 1] : 0;
        rowptr[gi] = rowptr[gi] - cnt[gi] + add;
        cnt[gi] = 0;
    }
    if (gi == 0) rowptr[n] = NEDGES;
}

__global__ void place_k(const int* __restrict__ row, const int* __restrict__ col,
                        const float* __restrict__ w, const float* __restrict__ dis,
                        const int* __restrict__ rowptr, int* __restrict__ cursor,
                        int* __restrict__ src, float* __restrict__ val, int E) {
    int e = blockIdx.x * 256 + threadIdx.x;
    if (e < E) {
        int r = row[e], c = col[e];
        int pos = rowptr[c] + atomicAdd(&cursor[c], 1);
        src[pos] = r;
        val[pos] = dis[r] * w[e] * dis[c];
    }
}

// ---------------- W2 -> bf16 transposed: Wt[c][k] = W[k][c] ----------------
__global__ void wconv_k(const float* __restrict__ W, unsigned short* __restrict__ Wt) {
    int idx = blockIdx.x * 256 + threadIdx.x;
    if (idx < 128 * 128) {
        int c = idx >> 7, k = idx & 127;
        Wt[c * 128 + k] = f2bf(W[k * 128 + c]);
    }
}

// ---------------- gather-aggregate (bf16 h) + self-loop + bias + relu, bf16 out ----
__global__ __launch_bounds__(256) void agg_k(const int* __restrict__ rowptr,
                                             const int* __restrict__ src,
                                             const float* __restrict__ val,
                                             const unsigned int* __restrict__ h,
                                             const float* __restrict__ dis,
                                             const float* __restrict__ bias,
                                             unsigned int* __restrict__ out) {
    int node = blockIdx.x * 4 + (threadIdx.x >> 6);
    if (node >= NNODES) return;
    int lane = threadIdx.x & 63;  // handles feats 2*lane, 2*lane+1 (one uint)

    float d = dis[node];
    float2 hc = bfpair(h[node * 64 + lane]);
    float2 acc;
    acc.x = d * d * hc.x;
    acc.y = d * d * hc.y;

    int j = rowptr[node], jend = rowptr[node + 1];
    for (; j + 1 < jend; j += 2) {
        int   r0 = src[j],     r1 = src[j + 1];
        float v0 = val[j],     v1 = val[j + 1];
        float2 a = bfpair(h[r0 * 64 + lane]);
        float2 b = bfpair(h[r1 * 64 + lane]);
        acc.x = fmaf(v0, a.x, acc.x); acc.y = fmaf(v0, a.y, acc.y);
        acc.x = fmaf(v1, b.x, acc.x); acc.y = fmaf(v1, b.y, acc.y);
    }
    if (j < jend) {
        int r = src[j]; float v = val[j];
        float2 a = bfpair(h[r * 64 + lane]);
        acc.x = fmaf(v, a.x, acc.x); acc.y = fmaf(v, a.y, acc.y);
    }

    float2 bv = ((const float2*)bias)[lane];
    acc.x = fmaxf(acc.x + bv.x, 0.f);
    acc.y = fmaxf(acc.y + bv.y, 0.f);
    out[node * 64 + lane] = packbf(acc.x, acc.y);
}

// ---------------- GEMM2 (MFMA bf16): C[N,128] = A[N,128] @ W2, bf16 in/out ---------
// A row-major bf16; Wt pre-transposed [n][k] bf16. 128x128 tile, 4 waves, each wave
// 4x4 grid of 16x16 tiles, BK=64 staged in LDS (stride 72 bf16 = 144 B, 16B-aligned,
// rotates banks by 4 words/row -> 2-way max on frag reads).
__global__ __launch_bounds__(256) void gemm2_k(const unsigned short* __restrict__ A,
                                               const unsigned short* __restrict__ Wt,
                                               unsigned short* __restrict__ C, int N) {
    __shared__ unsigned short As[128 * 72];
    __shared__ unsigned short Ws[128 * 72];
    const int tid  = threadIdx.x;
    const int wave = tid >> 6, lane = tid & 63;
    const int quad = lane >> 4, l16 = lane & 15;
    const int wm = wave >> 1, wn = wave & 1;   // 64x64 region per wave
    const int row0 = blockIdx.x * 128;

    f32x4 acc[4][4];
#pragma unroll
    for (int i = 0; i < 4; i++)
#pragma unroll
        for (int j = 0; j < 4; j++) acc[i][j] = (f32x4)0.f;

    for (int c = 0; c < 2; c++) {
        const int k0g = c * 64;
        __syncthreads();
#pragma unroll
        for (int j = 0; j < 4; j++) {
            int idx = tid + j * 256;          // 1024 x 16B units
            int r = idx >> 3, ku = idx & 7;
            uint4 va = make_uint4(0u, 0u, 0u, 0u);
            if (row0 + r < N)
                va = *(const uint4*)&A[(size_t)(row0 + r) * 128 + k0g + ku * 8];
            *(uint4*)&As[r * 72 + ku * 8] = va;
            uint4 vw = *(const uint4*)&Wt[(size_t)r * 128 + k0g + ku * 8];
            *(uint4*)&Ws[r * 72 + ku * 8] = vw;
        }
        __syncthreads();
#pragma unroll
        for (int kc = 0; kc < 2; kc++) {
            const int kl = kc * 32 + quad * 8;
            bf16x8 af[4], bfr[4];
#pragma unroll
            for (int t = 0; t < 4; t++) {
                af[t]  = *(const bf16x8*)&As[(wm * 64 + t * 16 + l16) * 72 + kl];
                bfr[t] = *(const bf16x8*)&Ws[(wn * 64 + t * 16 + l16) * 72 + kl];
            }
#pragma unroll
            for (int tm = 0; tm < 4; tm++)
#pragma unroll
                for (int tn = 0; tn < 4; tn++)
                    acc[tm][tn] = __builtin_amdgcn_mfma_f32_16x16x32_bf16(
                        af[tm], bfr[tn], acc[tm][tn], 0, 0, 0);
        }
    }

#pragma unroll
    for (int tm = 0; tm < 4; tm++) {
        const int rbase = row0 + wm * 64 + tm * 16 + quad * 4;
#pragma unroll
        for (int tn = 0; tn < 4; tn++) {
            const int col = wn * 64 + tn * 16 + l16;
#pragma unroll
            for (int r = 0; r < 4; r++) {
                if (rbase + r < N)
                    C[(size_t)(rbase + r) * 128 + col] = f2bf(acc[tm][tn][r]);
            }
        }
    }
}

// ---------------- GEMM1: C[N,128](bf16) = x[N,26](f32) @ W1[26,128](f32) -----------
__global__ __launch_bounds__(256) void gemm1_k(const float* __restrict__ A,
                                               const float* __restrict__ W,
                                               unsigned short* __restrict__ C, int N) {
    constexpr int AP = 132;
    __shared__ float As[26 * AP];
    __shared__ float Ws[26 * 128];
    const int tid  = threadIdx.x;
    const int wave = tid >> 6, lane = tid & 63;
    const int cg = (lane & 7) | ((wave & 1) << 3);
    const int rg = ((lane >> 3) & 7) | ((wave >> 1) << 3);
    const int row0 = blockIdx.x * 128;
    const int nrows = min(128, N - row0);

    for (int i = tid; i < 128 * 26; i += 256) {
        int r = i / 26, k = i - r * 26;
        As[k * AP + r] = (r < nrows) ? A[(size_t)row0 * 26 + i] : 0.f;
    }
    for (int i = tid; i < 26 * 128; i += 256) Ws[i] = W[i];

    float acc[8][8];
#pragma unroll
    for (int i = 0; i < 8; i++)
#pragma unroll
        for (int jj = 0; jj < 8; jj++) acc[i][jj] = 0.f;

    __syncthreads();
#pragma unroll 2
    for (int k = 0; k < 26; k++) {
        float4 a0 = *(const float4*)&As[k * AP + rg * 8];
        float4 a1 = *(const float4*)&As[k * AP + rg * 8 + 4];
        float4 w0 = *(const float4*)&Ws[k * 128 + cg * 8];
        float4 w1 = *(const float4*)&Ws[k * 128 + cg * 8 + 4];
        float a[8] = {a0.x, a0.y, a0.z, a0.w, a1.x, a1.y, a1.z, a1.w};
        float w[8] = {w0.x, w0.y, w0.z, w0.w, w1.x, w1.y, w1.z, w1.w};
#pragma unroll
        for (int i = 0; i < 8; i++)
#pragma unroll
            for (int jj = 0; jj < 8; jj++)
                acc[i][jj] = fmaf(a[i], w[jj], acc[i][jj]);
    }

#pragma unroll
    for (int i = 0; i < 8; i++) {
        int r = rg * 8 + i;
        if (r < nrows) {
            uint4 o;
            o.x = packbf(acc[i][0], acc[i][1]);
            o.y = packbf(acc[i][2], acc[i][3]);
            o.z = packbf(acc[i][4], acc[i][5]);
            o.w = packbf(acc[i][6], acc[i][7]);
            *(uint4*)&C[(size_t)(row0 + r) * 128 + cg * 8] = o;
        }
    }
}

// ---------------- fc: out[N,26](f32) = h[N,128](bf16) @ Wfc[128,26](f32) + bfc -----
__global__ __launch_bounds__(256) void gemmfc_k(const unsigned short* __restrict__ A,
                                                const float* __restrict__ W,
                                                const float* __restrict__ bias,
                                                float* __restrict__ C, int N) {
    constexpr int AP = 132;
    __shared__ float As[32 * AP];
    __shared__ float Ws[32 * 32];
    __shared__ float bs[32];
    const int tid  = threadIdx.x;
    const int wave = tid >> 6, lane = tid & 63;
    const int cg = lane & 7;
    const int rg = ((lane >> 3) & 7) | (wave << 3);
    const int row0 = blockIdx.x * 128;
    const int nrows = min(128, N - row0);

    if (tid < 32) bs[tid] = (tid < NCLASS) ? bias[tid] : 0.f;

    float acc[4][4];
#pragma unroll
    for (int i = 0; i < 4; i++)
#pragma unroll
        for (int jj = 0; jj < 4; jj++) acc[i][jj] = 0.f;

    for (int k0 = 0; k0 < 128; k0 += 32) {
        __syncthreads();
        for (int i = tid; i < 128 * 32; i += 256) {
            int r = i >> 5, k = i & 31;
            As[k * AP + r] = (r < nrows) ? bf2f(A[(size_t)(row0 + r) * 128 + k0 + k]) : 0.f;
        }
        for (int i = tid; i < 32 * 32; i += 256) {
            int k = i >> 5, c = i & 31;
            Ws[i] = (c < NCLASS) ? W[(size_t)(k0 + k) * NCLASS + c] : 0.f;
        }
        __syncthreads();
#pragma unroll 4
        for (int k = 0; k < 32; k++) {
            float4 a0 = *(const float4*)&As[k * AP + rg * 4];
            float4 w0 = *(const float4*)&Ws[k * 32 + cg * 4];
            float a[4] = {a0.x, a0.y, a0.z, a0.w};
            float w[4] = {w0.x, w0.y, w0.z, w0.w};
#pragma unroll
            for (int i = 0; i < 4; i++)
#pragma unroll
                for (int jj = 0; jj < 4; jj++)
                    acc[i][jj] = fmaf(a[i], w[jj], acc[i][jj]);
        }
    }

    const int c0 = cg * 4;
#pragma unroll
    for (int i = 0; i < 4; i++) {
        int r = rg * 4 + i;
        if (r < nrows && c0 < NCLASS) {
            float* dst = &C[(size_t)(row0 + r) * NCLASS + c0];
            if (c0 + 3 < NCLASS) {
                float4 v = {acc[i][0] + bs[c0], acc[i][1] + bs[c0 + 1],
                            acc[i][2] + bs[c0 + 2], acc[i][3] + bs[c0 + 3]};
                *(float4*)dst = v;
            } else {
                dst[0] = acc[i][0] + bs[c0];
                dst[1] = acc[i][1] + bs[c0 + 1];
            }
        }
    }
}

extern "C" void kernel_launch(void* const* d_in, const int* in_sizes, int n_in,
                              void* d_out, int out_size, void* d_ws, size_t ws_size,
                              hipStream_t stream) {
    const float* x   = (const float*)d_in[0];
    const int*   ei  = (const int*)d_in[1];
    const float* ew  = (const float*)d_in[2];
    const float* W1  = (const float*)d_in[3];
    const float* b1  = (const float*)d_in[4];
    const float* W2  = (const float*)d_in[5];
    const float* b2  = (const float*)d_in[6];
    const float* Wfc = (const float*)d_in[7];
    const float* bfc = (const float*)d_in[8];
    float* out = (float*)d_out;

    const int N = NNODES, E = NEDGES;
    const int* erow = ei;
    const int* ecol = ei + E;

    // ws layout (float units):
    // dis[100000] cnt[100000] rowptr[100004] aux[512] src[600000] val[600000]
    // wt16[8192] hA16[6.4M] hB16[6.4M]   total ~57 MB
    float* fws    = (float*)d_ws;
    float* dis    = fws;
    int*   cnt    = (int*)(fws + 100000);
    int*   rowptr = (int*)(fws + 200000);
    int*   aux    = (int*)(fws + 300004);
    int*   src    = (int*)(fws + 300516);
    float* val    = fws + 900516;
    unsigned short* wt16 = (unsigned short*)(fws + 1500516);
    unsigned short* hA16 = (unsigned short*)(fws + 1508708);   // 16B aligned
    unsigned short* hB16 = (unsigned short*)(fws + 7908708);   // 16B aligned

    const int gN = (N + 255) / 256;
    const int gE = (E + 255) / 256;
    const int g128 = (N + 127) / 128;  // 782

    // ---- gcn_norm + CSR build ----
    init_k<<<gN, 256, 0, stream>>>(dis, cnt, N);
    degcnt_k<<<gE, 256, 0, stream>>>(ecol, ew, dis, cnt, E);
    dinv_k<<<gN, 256, 0, stream>>>(dis, N);
    scan1_k<<<NBLK, 256, 0, stream>>>(cnt, rowptr, aux, N);
    scan2_k<<<1, 512, 0, stream>>>(aux, NBLK);
    scan3_k<<<NBLK, 256, 0, stream>>>(rowptr, cnt, aux, N);
    place_k<<<gE, 256, 0, stream>>>(erow, ecol, ew, dis, rowptr, cnt, src, val, E);
    wconv_k<<<64, 256, 0, stream>>>(W2, wt16);

    // ---- layer 1: x@W1 -> gather-agg(+b1, relu) ----
    gemm1_k<<<g128, 256, 0, stream>>>(x, W1, hA16, N);
    agg_k<<<N / 4, 256, 0, stream>>>(rowptr, src, val, (const unsigned int*)hA16, dis, b1,
                                     (unsigned int*)hB16);

    // ---- layer 2: h@W2 (MFMA) -> gather-agg(+b2, relu) ----
    gemm2_k<<<g128, 256, 0, stream>>>(hB16, wt16, hA16, N);
    agg_k<<<N / 4, 256, 0, stream>>>(rowptr, src, val, (const unsigned int*)hA16, dis, b2,
                                     (unsigned int*)hB16);

    // ---- fc ----
    gemmfc_k<<<g128, 256, 0, stream>>>(hB16, Wfc, bfc, out, N);
}

// Round 6
// 311.934 us; speedup vs baseline: 3.2743x; 1.1315x over previous
//
#include <hip/hip_runtime.h>

#define NNODES 100000
#define NEDGES 600000
#define NCLASS 26
#define HID    128
#define NBLK   391   // ceil(NNODES/256)

typedef __attribute__((ext_vector_type(8))) short bf16x8;  // 8 bf16 = 4 VGPRs
typedef __attribute__((ext_vector_type(4))) float f32x4;

__device__ inline unsigned short f2bf(float f) {  // RNE fp32->bf16
    unsigned int u = __float_as_uint(f);
    u += 0x7fffu + ((u >> 16) & 1u);
    return (unsigned short)(u >> 16);
}
__device__ inline float bf2f(unsigned short b) {
    return __uint_as_float((unsigned int)b << 16);
}
__device__ inline unsigned int packbf(float a, float b) {
    return (unsigned int)f2bf(a) | ((unsigned int)f2bf(b) << 16);
}
__device__ inline float2 bfpair(unsigned int p) {  // lo ushort = first feat
    float2 r;
    r.x = __uint_as_float(p << 16);
    r.y = __uint_as_float(p & 0xffff0000u);
    return r;
}

// ---------------- init: pc=0 (packed cnt|wsum) ----------------
__global__ void init_k(unsigned long long* __restrict__ pc, int n) {
    int i = blockIdx.x * 256 + threadIdx.x;
    if (i < n) pc[i] = 0ull;
}

// One 64-bit atomic per edge: hi32 = in-degree count, lo32 = sum(w) in 2^26 fixpt.
// Max node wsum capacity 64.0 (max in-degree ~25 for this random graph); quant
// error 2^-27 per edge -- negligible vs bf16 output granularity.
__global__ void degcnt_k(const int* __restrict__ col, const float* __restrict__ w,
                         unsigned long long* __restrict__ pc, int E) {
    int e = blockIdx.x * 256 + threadIdx.x;
    if (e < E) {
        unsigned int q = (unsigned int)(w[e] * 67108864.0f + 0.5f);
        atomicAdd(&pc[col[e]], (1ull << 32) | (unsigned long long)q);
    }
}

// ---------------- scan1 (+ fused dinv): cnt -> block-wise inclusive scan ----------
__global__ void scan1_k(const unsigned long long* __restrict__ pc,
                        int* __restrict__ incl, int* __restrict__ aux,
                        float* __restrict__ dis, int n) {
    __shared__ int s[256];
    int t = threadIdx.x, gi = blockIdx.x * 256 + t;
    unsigned long long p = (gi < n) ? pc[gi] : 0ull;
    s[t] = (int)(p >> 32);
    if (gi < n) {
        float deg = 1.0f + (float)(unsigned int)(p & 0xffffffffu) * (1.0f / 67108864.0f);
        dis[gi] = rsqrtf(deg);   // deg >= 1 always (self-loop)
    }
    __syncthreads();
    for (int off = 1; off < 256; off <<= 1) {
        int x = (t >= off) ? s[t - off] : 0;
        __syncthreads();
        s[t] += x;
        __syncthreads();
    }
    if (gi < n) incl[gi] = s[t];
    if (t == 255) aux[blockIdx.x] = s[255];
}

__global__ void scan2_k(int* __restrict__ aux, int n) {
    __shared__ int s[512];
    int t = threadIdx.x;
    s[t] = (t < n) ? aux[t] : 0;
    __syncthreads();
    for (int off = 1; off < 512; off <<= 1) {
        int x = (t >= off) ? s[t - off] : 0;
        __syncthreads();
        s[t] += x;
        __syncthreads();
    }
    if (t < n) aux[t] = s[t];
}

// incl -> exclusive rowptr; zero cursor
__global__ void scan3_k(int* __restrict__ rowptr, const unsigned long long* __restrict__ pc,
                        int* __restrict__ cursor, const int* __restrict__ aux, int n) {
    int gi = blockIdx.x * 256 + threadIdx.x;
    if (gi < n) {
        int add = (blockIdx.x > 0) ? aux[blockIdx.x - 1] : 0;
        rowptr[gi] = rowptr[gi] - (int)(pc[gi] >> 32) + add;
        cursor[gi] = 0;
    }
    if (gi == 0) rowptr[n] = NEDGES;
}

// ---------------- place edges into CSR: meta[pos] = (src, norm-bits) --------------
__global__ void place_k(const int* __restrict__ row, const int* __restrict__ col,
                        const float* __restrict__ w, const float* __restrict__ dis,
                        const int* __restrict__ rowptr, int* __restrict__ cursor,
                        uint2* __restrict__ meta, int E) {
    int e = blockIdx.x * 256 + threadIdx.x;
    if (e < E) {
        int r = row[e], c = col[e];
        int pos = rowptr[c] + atomicAdd(&cursor[c], 1);
        float v = dis[r] * w[e] * dis[c];
        meta[pos] = make_uint2((unsigned int)r, __float_as_uint(v));
    }
}

// ---------------- W2 -> bf16 transposed: Wt[c][k] = W[k][c] ----------------
__global__ void wconv_k(const float* __restrict__ W, unsigned short* __restrict__ Wt) {
    int idx = blockIdx.x * 256 + threadIdx.x;
    if (idx < 128 * 128) {
        int c = idx >> 7, k = idx & 127;
        Wt[c * 128 + k] = f2bf(W[k * 128 + c]);
    }
}

// ---------------- gather-aggregate (bf16 h) + self-loop + bias + relu, bf16 out ----
__global__ __launch_bounds__(256) void agg_k(const int* __restrict__ rowptr,
                                             const uint2* __restrict__ meta,
                                             const unsigned int* __restrict__ h,
                                             const float* __restrict__ dis,
                                             const float* __restrict__ bias,
                                             unsigned int* __restrict__ out) {
    int node = blockIdx.x * 4 + (threadIdx.x >> 6);
    if (node >= NNODES) return;
    int lane = threadIdx.x & 63;  // handles feats 2*lane, 2*lane+1 (one uint)

    float d = dis[node];
    float2 hc = bfpair(h[node * 64 + lane]);
    float2 acc;
    acc.x = d * d * hc.x;
    acc.y = d * d * hc.y;

    int j = rowptr[node], jend = rowptr[node + 1];
    for (; j + 3 < jend; j += 4) {
        uint2 m0 = meta[j],     m1 = meta[j + 1];
        uint2 m2 = meta[j + 2], m3 = meta[j + 3];
        float2 a0 = bfpair(h[m0.x * 64 + lane]);
        float2 a1 = bfpair(h[m1.x * 64 + lane]);
        float2 a2 = bfpair(h[m2.x * 64 + lane]);
        float2 a3 = bfpair(h[m3.x * 64 + lane]);
        float v0 = __uint_as_float(m0.y), v1 = __uint_as_float(m1.y);
        float v2 = __uint_as_float(m2.y), v3 = __uint_as_float(m3.y);
        acc.x = fmaf(v0, a0.x, acc.x); acc.y = fmaf(v0, a0.y, acc.y);
        acc.x = fmaf(v1, a1.x, acc.x); acc.y = fmaf(v1, a1.y, acc.y);
        acc.x = fmaf(v2, a2.x, acc.x); acc.y = fmaf(v2, a2.y, acc.y);
        acc.x = fmaf(v3, a3.x, acc.x); acc.y = fmaf(v3, a3.y, acc.y);
    }
    for (; j < jend; j++) {
        uint2 m = meta[j];
        float v = __uint_as_float(m.y);
        float2 a = bfpair(h[m.x * 64 + lane]);
        acc.x = fmaf(v, a.x, acc.x); acc.y = fmaf(v, a.y, acc.y);
    }

    float2 bv = ((const float2*)bias)[lane];
    acc.x = fmaxf(acc.x + bv.x, 0.f);
    acc.y = fmaxf(acc.y + bv.y, 0.f);
    out[node * 64 + lane] = packbf(acc.x, acc.y);
}

// ---------------- GEMM2 (MFMA bf16): C[N,128] = A[N,128] @ W2, bf16 in/out ---------
__global__ __launch_bounds__(256) void gemm2_k(const unsigned short* __restrict__ A,
                                               const unsigned short* __restrict__ Wt,
                                               unsigned short* __restrict__ C, int N) {
    __shared__ unsigned short As[128 * 72];
    __shared__ unsigned short Ws[128 * 72];
    const int tid  = threadIdx.x;
    const int wave = tid >> 6, lane = tid & 63;
    const int quad = lane >> 4, l16 = lane & 15;
    const int wm = wave >> 1, wn = wave & 1;   // 64x64 region per wave
    const int row0 = blockIdx.x * 128;

    f32x4 acc[4][4];
#pragma unroll
    for (int i = 0; i < 4; i++)
#pragma unroll
        for (int j = 0; j < 4; j++) acc[i][j] = (f32x4)0.f;

    for (int c = 0; c < 2; c++) {
        const int k0g = c * 64;
        __syncthreads();
#pragma unroll
        for (int j = 0; j < 4; j++) {
            int idx = tid + j * 256;          // 1024 x 16B units
            int r = idx >> 3, ku = idx & 7;
            uint4 va = make_uint4(0u, 0u, 0u, 0u);
            if (row0 + r < N)
                va = *(const uint4*)&A[(size_t)(row0 + r) * 128 + k0g + ku * 8];
            *(uint4*)&As[r * 72 + ku * 8] = va;
            uint4 vw = *(const uint4*)&Wt[(size_t)r * 128 + k0g + ku * 8];
            *(uint4*)&Ws[r * 72 + ku * 8] = vw;
        }
        __syncthreads();
#pragma unroll
        for (int kc = 0; kc < 2; kc++) {
            const int kl = kc * 32 + quad * 8;
            bf16x8 af[4], bfr[4];
#pragma unroll
            for (int t = 0; t < 4; t++) {
                af[t]  = *(const bf16x8*)&As[(wm * 64 + t * 16 + l16) * 72 + kl];
                bfr[t] = *(const bf16x8*)&Ws[(wn * 64 + t * 16 + l16) * 72 + kl];
            }
#pragma unroll
            for (int tm = 0; tm < 4; tm++)
#pragma unroll
                for (int tn = 0; tn < 4; tn++)
                    acc[tm][tn] = __builtin_amdgcn_mfma_f32_16x16x32_bf16(
                        af[tm], bfr[tn], acc[tm][tn], 0, 0, 0);
        }
    }

#pragma unroll
    for (int tm = 0; tm < 4; tm++) {
        const int rbase = row0 + wm * 64 + tm * 16 + quad * 4;
#pragma unroll
        for (int tn = 0; tn < 4; tn++) {
            const int col = wn * 64 + tn * 16 + l16;
#pragma unroll
            for (int r = 0; r < 4; r++) {
                if (rbase + r < N)
                    C[(size_t)(rbase + r) * 128 + col] = f2bf(acc[tm][tn][r]);
            }
        }
    }
}

// ---------------- GEMM1: C[N,128](bf16) = x[N,26](f32) @ W1[26,128](f32) -----------
__global__ __launch_bounds__(256) void gemm1_k(const float* __restrict__ A,
                                               const float* __restrict__ W,
                                               unsigned short* __restrict__ C, int N) {
    constexpr int AP = 132;
    __shared__ float As[26 * AP];
    __shared__ float Ws[26 * 128];
    const int tid  = threadIdx.x;
    const int wave = tid >> 6, lane = tid & 63;
    const int cg = (lane & 7) | ((wave & 1) << 3);
    const int rg = ((lane >> 3) & 7) | ((wave >> 1) << 3);
    const int row0 = blockIdx.x * 128;
    const int nrows = min(128, N - row0);

    for (int i = tid; i < 128 * 26; i += 256) {
        int r = i / 26, k = i - r * 26;
        As[k * AP + r] = (r < nrows) ? A[(size_t)row0 * 26 + i] : 0.f;
    }
    for (int i = tid; i < 26 * 128; i += 256) Ws[i] = W[i];

    float acc[8][8];
#pragma unroll
    for (int i = 0; i < 8; i++)
#pragma unroll
        for (int jj = 0; jj < 8; jj++) acc[i][jj] = 0.f;

    __syncthreads();
#pragma unroll 2
    for (int k = 0; k < 26; k++) {
        float4 a0 = *(const float4*)&As[k * AP + rg * 8];
        float4 a1 = *(const float4*)&As[k * AP + rg * 8 + 4];
        float4 w0 = *(const float4*)&Ws[k * 128 + cg * 8];
        float4 w1 = *(const float4*)&Ws[k * 128 + cg * 8 + 4];
        float a[8] = {a0.x, a0.y, a0.z, a0.w, a1.x, a1.y, a1.z, a1.w};
        float w[8] = {w0.x, w0.y, w0.z, w0.w, w1.x, w1.y, w1.z, w1.w};
#pragma unroll
        for (int i = 0; i < 8; i++)
#pragma unroll
            for (int jj = 0; jj < 8; jj++)
                acc[i][jj] = fmaf(a[i], w[jj], acc[i][jj]);
    }

#pragma unroll
    for (int i = 0; i < 8; i++) {
        int r = rg * 8 + i;
        if (r < nrows) {
            uint4 o;
            o.x = packbf(acc[i][0], acc[i][1]);
            o.y = packbf(acc[i][2], acc[i][3]);
            o.z = packbf(acc[i][4], acc[i][5]);
            o.w = packbf(acc[i][6], acc[i][7]);
            *(uint4*)&C[(size_t)(row0 + r) * 128 + cg * 8] = o;
        }
    }
}

// ---------------- fc: out[N,26](f32) = h[N,128](bf16) @ Wfc[128,26](f32) + bfc -----
__global__ __launch_bounds__(256) void gemmfc_k(const unsigned short* __restrict__ A,
                                                const float* __restrict__ W,
                                                const float* __restrict__ bias,
                                                float* __restrict__ C, int N) {
    constexpr int AP = 132;
    __shared__ float As[32 * AP];
    __shared__ float Ws[32 * 32];
    __shared__ float bs[32];
    const int tid  = threadIdx.x;
    const int wave = tid >> 6, lane = tid & 63;
    const int cg = lane & 7;
    const int rg = ((lane >> 3) & 7) | (wave << 3);
    const int row0 = blockIdx.x * 128;
    const int nrows = min(128, N - row0);

    if (tid < 32) bs[tid] = (tid < NCLASS) ? bias[tid] : 0.f;

    float acc[4][4];
#pragma unroll
    for (int i = 0; i < 4; i++)
#pragma unroll
        for (int jj = 0; jj < 4; jj++) acc[i][jj] = 0.f;

    for (int k0 = 0; k0 < 128; k0 += 32) {
        __syncthreads();
        for (int i = tid; i < 128 * 32; i += 256) {
            int r = i >> 5, k = i & 31;
            As[k * AP + r] = (r < nrows) ? bf2f(A[(size_t)(row0 + r) * 128 + k0 + k]) : 0.f;
        }
        for (int i = tid; i < 32 * 32; i += 256) {
            int k = i >> 5, c = i & 31;
            Ws[i] = (c < NCLASS) ? W[(size_t)(k0 + k) * NCLASS + c] : 0.f;
        }
        __syncthreads();
#pragma unroll 4
        for (int k = 0; k < 32; k++) {
            float4 a0 = *(const float4*)&As[k * AP + rg * 4];
            float4 w0 = *(const float4*)&Ws[k * 32 + cg * 4];
            float a[4] = {a0.x, a0.y, a0.z, a0.w};
            float w[4] = {w0.x, w0.y, w0.z, w0.w};
#pragma unroll
            for (int i = 0; i < 4; i++)
#pragma unroll
                for (int jj = 0; jj < 4; jj++)
                    acc[i][jj] = fmaf(a[i], w[jj], acc[i][jj]);
        }
    }

    const int c0 = cg * 4;
#pragma unroll
    for (int i = 0; i < 4; i++) {
        int r = rg * 4 + i;
        if (r < nrows && c0 < NCLASS) {
            float* dst = &C[(size_t)(row0 + r) * NCLASS + c0];
            if (c0 + 3 < NCLASS) {
                float4 v = {acc[i][0] + bs[c0], acc[i][1] + bs[c0 + 1],
                            acc[i][2] + bs[c0 + 2], acc[i][3] + bs[c0 + 3]};
                *(float4*)dst = v;
            } else {
                dst[0] = acc[i][0] + bs[c0];
                dst[1] = acc[i][1] + bs[c0 + 1];
            }
        }
    }
}

extern "C" void kernel_launch(void* const* d_in, const int* in_sizes, int n_in,
                              void* d_out, int out_size, void* d_ws, size_t ws_size,
                              hipStream_t stream) {
    const float* x   = (const float*)d_in[0];
    const int*   ei  = (const int*)d_in[1];
    const float* ew  = (const float*)d_in[2];
    const float* W1  = (const float*)d_in[3];
    const float* b1  = (const float*)d_in[4];
    const float* W2  = (const float*)d_in[5];
    const float* b2  = (const float*)d_in[6];
    const float* Wfc = (const float*)d_in[7];
    const float* bfc = (const float*)d_in[8];
    float* out = (float*)d_out;

    const int N = NNODES, E = NEDGES;
    const int* erow = ei;
    const int* ecol = ei + E;

    // ws layout (float units):
    // dis[100000] pc[200000(ull)] rowptr[100004] aux[512] cursor[100000]
    // meta[1200000(uint2)] wt16[8192] hA16[6.4M] hB16[6.4M]  ~58 MB
    float* fws    = (float*)d_ws;
    float* dis    = fws;
    unsigned long long* pc = (unsigned long long*)(fws + 100000);  // byte off 400000, 8B-aligned
    int*   rowptr = (int*)(fws + 300000);
    int*   aux    = (int*)(fws + 400004);
    int*   cursor = (int*)(fws + 400516);
    uint2* meta   = (uint2*)(fws + 500516);                        // byte off 2002064, 8B-aligned
    unsigned short* wt16 = (unsigned short*)(fws + 1700516);
    unsigned short* hA16 = (unsigned short*)(fws + 1708708);       // 16B-aligned
    unsigned short* hB16 = (unsigned short*)(fws + 8108708);       // 16B-aligned

    const int gN = (N + 255) / 256;
    const int gE = (E + 255) / 256;
    const int g128 = (N + 127) / 128;  // 782

    // ---- gcn_norm + CSR build ----
    init_k<<<gN, 256, 0, stream>>>(pc, N);
    degcnt_k<<<gE, 256, 0, stream>>>(ecol, ew, pc, E);
    scan1_k<<<NBLK, 256, 0, stream>>>(pc, rowptr, aux, dis, N);
    scan2_k<<<1, 512, 0, stream>>>(aux, NBLK);
    scan3_k<<<NBLK, 256, 0, stream>>>(rowptr, pc, cursor, aux, N);
    place_k<<<gE, 256, 0, stream>>>(erow, ecol, ew, dis, rowptr, cursor, meta, E);
    wconv_k<<<64, 256, 0, stream>>>(W2, wt16);

    // ---- layer 1: x@W1 -> gather-agg(+b1, relu) ----
    gemm1_k<<<g128, 256, 0, stream>>>(x, W1, hA16, N);
    agg_k<<<N / 4, 256, 0, stream>>>(rowptr, meta, (const unsigned int*)hA16, dis, b1,
                                     (unsigned int*)hB16);

    // ---- layer 2: h@W2 (MFMA) -> gather-agg(+b2, relu) ----
    gemm2_k<<<g128, 256, 0, stream>>>(hB16, wt16, hA16, N);
    agg_k<<<N / 4, 256, 0, stream>>>(rowptr, meta, (const unsigned int*)hA16, dis, b2,
                                     (unsigned int*)hB16);

    // ---- fc ----
    gemmfc_k<<<g128, 256, 0, stream>>>(hB16, Wfc, bfc, out, N);
}

// Round 7
// 301.727 us; speedup vs baseline: 3.3850x; 1.0338x over previous
//
#include <hip/hip_runtime.h>

#define NNODES 100000
#define NEDGES 600000
#define NCLASS 26
#define HID    128
#define NBLK   391   // ceil(NNODES/256)

typedef __attribute__((ext_vector_type(8))) short bf16x8;  // 8 bf16 = 4 VGPRs
typedef __attribute__((ext_vector_type(4))) float f32x4;

__device__ inline unsigned short f2bf(float f) {  // RNE fp32->bf16
    unsigned int u = __float_as_uint(f);
    u += 0x7fffu + ((u >> 16) & 1u);
    return (unsigned short)(u >> 16);
}
__device__ inline float bf2f(unsigned short b) {
    return __uint_as_float((unsigned int)b << 16);
}
__device__ inline unsigned int packbf(float a, float b) {
    return (unsigned int)f2bf(a) | ((unsigned int)f2bf(b) << 16);
}
__device__ inline float2 bfpair(unsigned int p) {  // lo ushort = first feat
    float2 r;
    r.x = __uint_as_float(p << 16);
    r.y = __uint_as_float(p & 0xffff0000u);
    return r;
}

// ---------------- init: pc=0 (packed cnt|wsum) ----------------
__global__ void init_k(unsigned long long* __restrict__ pc, int n) {
    int i = blockIdx.x * 256 + threadIdx.x;
    if (i < n) pc[i] = 0ull;
}

// One 64-bit atomic per edge: hi32 = in-degree count, lo32 = sum(w) in 2^26 fixpt.
__global__ void degcnt_k(const int* __restrict__ col, const float* __restrict__ w,
                         unsigned long long* __restrict__ pc, int E) {
    int e = blockIdx.x * 256 + threadIdx.x;
    if (e < E) {
        unsigned int q = (unsigned int)(w[e] * 67108864.0f + 0.5f);
        atomicAdd(&pc[col[e]], (1ull << 32) | (unsigned long long)q);
    }
}

// ---------------- scan1 (+ fused dinv): cnt -> block-wise inclusive scan ----------
__global__ void scan1_k(const unsigned long long* __restrict__ pc,
                        int* __restrict__ incl, int* __restrict__ aux,
                        float* __restrict__ dis, int n) {
    __shared__ int s[256];
    int t = threadIdx.x, gi = blockIdx.x * 256 + t;
    unsigned long long p = (gi < n) ? pc[gi] : 0ull;
    s[t] = (int)(p >> 32);
    if (gi < n) {
        float deg = 1.0f + (float)(unsigned int)(p & 0xffffffffu) * (1.0f / 67108864.0f);
        dis[gi] = rsqrtf(deg);
    }
    __syncthreads();
    for (int off = 1; off < 256; off <<= 1) {
        int x = (t >= off) ? s[t - off] : 0;
        __syncthreads();
        s[t] += x;
        __syncthreads();
    }
    if (gi < n) incl[gi] = s[t];
    if (t == 255) aux[blockIdx.x] = s[255];
}

__global__ void scan2_k(int* __restrict__ aux, int n) {
    __shared__ int s[512];
    int t = threadIdx.x;
    s[t] = (t < n) ? aux[t] : 0;
    __syncthreads();
    for (int off = 1; off < 512; off <<= 1) {
        int x = (t >= off) ? s[t - off] : 0;
        __syncthreads();
        s[t] += x;
        __syncthreads();
    }
    if (t < n) aux[t] = s[t];
}

// incl -> exclusive rowptr; zero cursor
__global__ void scan3_k(int* __restrict__ rowptr, const unsigned long long* __restrict__ pc,
                        int* __restrict__ cursor, const int* __restrict__ aux, int n) {
    int gi = blockIdx.x * 256 + threadIdx.x;
    if (gi < n) {
        int add = (blockIdx.x > 0) ? aux[blockIdx.x - 1] : 0;
        rowptr[gi] = rowptr[gi] - (int)(pc[gi] >> 32) + add;
        cursor[gi] = 0;
    }
    if (gi == 0) rowptr[n] = NEDGES;
}

// ---------------- place edges into CSR: meta[pos] = (src, norm-bits) --------------
__global__ void place_k(const int* __restrict__ row, const int* __restrict__ col,
                        const float* __restrict__ w, const float* __restrict__ dis,
                        const int* __restrict__ rowptr, int* __restrict__ cursor,
                        uint2* __restrict__ meta, int E) {
    int e = blockIdx.x * 256 + threadIdx.x;
    if (e < E) {
        int r = row[e], c = col[e];
        int pos = rowptr[c] + atomicAdd(&cursor[c], 1);
        float v = dis[r] * w[e] * dis[c];
        meta[pos] = make_uint2((unsigned int)r, __float_as_uint(v));
    }
}

// ---------------- W2 -> bf16 transposed: Wt[c][k] = W[k][c] ----------------
__global__ void wconv_k(const float* __restrict__ W, unsigned short* __restrict__ Wt) {
    int idx = blockIdx.x * 256 + threadIdx.x;
    if (idx < 128 * 128) {
        int c = idx >> 7, k = idx & 127;
        Wt[c * 128 + k] = f2bf(W[k * 128 + c]);
    }
}

// ---------------- gather-aggregate: 2 nodes per wave (32 lanes / node) -------------
// Lane handles 4 feats (uint2 = 4 bf16). Each gather = 32 lanes x 8B = 256B row,
// fully coalesced. Two independent per-node edge streams per wave -> ~8 gathers
// in flight (MLP x2 vs round-6's one-node-per-wave).
__global__ __launch_bounds__(256) void agg_k(const int* __restrict__ rowptr,
                                             const uint2* __restrict__ meta,
                                             const uint2* __restrict__ h,
                                             const float* __restrict__ dis,
                                             const float* __restrict__ bias,
                                             uint2* __restrict__ out) {
    int node = blockIdx.x * 8 + (threadIdx.x >> 5);
    if (node >= NNODES) return;
    int lane = threadIdx.x & 31;  // feats 4*lane .. 4*lane+3

    float d = dis[node];
    uint2 hcu = h[node * 32 + lane];
    float2 h0 = bfpair(hcu.x), h1 = bfpair(hcu.y);
    float4 acc;
    acc.x = d * d * h0.x; acc.y = d * d * h0.y;
    acc.z = d * d * h1.x; acc.w = d * d * h1.y;

    int j = rowptr[node], jend = rowptr[node + 1];
    for (; j + 3 < jend; j += 4) {
        uint2 m0 = meta[j],     m1 = meta[j + 1];
        uint2 m2 = meta[j + 2], m3 = meta[j + 3];
        uint2 g0 = h[m0.x * 32 + lane];
        uint2 g1 = h[m1.x * 32 + lane];
        uint2 g2 = h[m2.x * 32 + lane];
        uint2 g3 = h[m3.x * 32 + lane];
        float v0 = __uint_as_float(m0.y), v1 = __uint_as_float(m1.y);
        float v2 = __uint_as_float(m2.y), v3 = __uint_as_float(m3.y);
        float2 a, b;
        a = bfpair(g0.x); b = bfpair(g0.y);
        acc.x = fmaf(v0, a.x, acc.x); acc.y = fmaf(v0, a.y, acc.y);
        acc.z = fmaf(v0, b.x, acc.z); acc.w = fmaf(v0, b.y, acc.w);
        a = bfpair(g1.x); b = bfpair(g1.y);
        acc.x = fmaf(v1, a.x, acc.x); acc.y = fmaf(v1, a.y, acc.y);
        acc.z = fmaf(v1, b.x, acc.z); acc.w = fmaf(v1, b.y, acc.w);
        a = bfpair(g2.x); b = bfpair(g2.y);
        acc.x = fmaf(v2, a.x, acc.x); acc.y = fmaf(v2, a.y, acc.y);
        acc.z = fmaf(v2, b.x, acc.z); acc.w = fmaf(v2, b.y, acc.w);
        a = bfpair(g3.x); b = bfpair(g3.y);
        acc.x = fmaf(v3, a.x, acc.x); acc.y = fmaf(v3, a.y, acc.y);
        acc.z = fmaf(v3, b.x, acc.z); acc.w = fmaf(v3, b.y, acc.w);
    }
    for (; j < jend; j++) {
        uint2 m = meta[j];
        float v = __uint_as_float(m.y);
        uint2 g = h[m.x * 32 + lane];
        float2 a = bfpair(g.x), b = bfpair(g.y);
        acc.x = fmaf(v, a.x, acc.x); acc.y = fmaf(v, a.y, acc.y);
        acc.z = fmaf(v, b.x, acc.z); acc.w = fmaf(v, b.y, acc.w);
    }

    float4 bv = ((const float4*)bias)[lane];
    acc.x = fmaxf(acc.x + bv.x, 0.f);
    acc.y = fmaxf(acc.y + bv.y, 0.f);
    acc.z = fmaxf(acc.z + bv.z, 0.f);
    acc.w = fmaxf(acc.w + bv.w, 0.f);
    out[node * 32 + lane] = make_uint2(packbf(acc.x, acc.y), packbf(acc.z, acc.w));
}

// ---------------- GEMM2 (MFMA bf16): C[N,128] = A[N,128] @ W2, bf16 in/out ---------
__global__ __launch_bounds__(256) void gemm2_k(const unsigned short* __restrict__ A,
                                               const unsigned short* __restrict__ Wt,
                                               unsigned short* __restrict__ C, int N) {
    __shared__ unsigned short As[128 * 72];
    __shared__ unsigned short Ws[128 * 72];
    const int tid  = threadIdx.x;
    const int wave = tid >> 6, lane = tid & 63;
    const int quad = lane >> 4, l16 = lane & 15;
    const int wm = wave >> 1, wn = wave & 1;   // 64x64 region per wave
    const int row0 = blockIdx.x * 128;

    f32x4 acc[4][4];
#pragma unroll
    for (int i = 0; i < 4; i++)
#pragma unroll
        for (int j = 0; j < 4; j++) acc[i][j] = (f32x4)0.f;

    for (int c = 0; c < 2; c++) {
        const int k0g = c * 64;
        __syncthreads();
#pragma unroll
        for (int j = 0; j < 4; j++) {
            int idx = tid + j * 256;          // 1024 x 16B units
            int r = idx >> 3, ku = idx & 7;
            uint4 va = make_uint4(0u, 0u, 0u, 0u);
            if (row0 + r < N)
                va = *(const uint4*)&A[(size_t)(row0 + r) * 128 + k0g + ku * 8];
            *(uint4*)&As[r * 72 + ku * 8] = va;
            uint4 vw = *(const uint4*)&Wt[(size_t)r * 128 + k0g + ku * 8];
            *(uint4*)&Ws[r * 72 + ku * 8] = vw;
        }
        __syncthreads();
#pragma unroll
        for (int kc = 0; kc < 2; kc++) {
            const int kl = kc * 32 + quad * 8;
            bf16x8 af[4], bfr[4];
#pragma unroll
            for (int t = 0; t < 4; t++) {
                af[t]  = *(const bf16x8*)&As[(wm * 64 + t * 16 + l16) * 72 + kl];
                bfr[t] = *(const bf16x8*)&Ws[(wn * 64 + t * 16 + l16) * 72 + kl];
            }
#pragma unroll
            for (int tm = 0; tm < 4; tm++)
#pragma unroll
                for (int tn = 0; tn < 4; tn++)
                    acc[tm][tn] = __builtin_amdgcn_mfma_f32_16x16x32_bf16(
                        af[tm], bfr[tn], acc[tm][tn], 0, 0, 0);
        }
    }

#pragma unroll
    for (int tm = 0; tm < 4; tm++) {
        const int rbase = row0 + wm * 64 + tm * 16 + quad * 4;
#pragma unroll
        for (int tn = 0; tn < 4; tn++) {
            const int col = wn * 64 + tn * 16 + l16;
#pragma unroll
            for (int r = 0; r < 4; r++) {
                if (rbase + r < N)
                    C[(size_t)(rbase + r) * 128 + col] = f2bf(acc[tm][tn][r]);
            }
        }
    }
}

// ---------------- GEMM1: C[N,128](bf16) = x[N,26](f32) @ W1[26,128](f32) -----------
__global__ __launch_bounds__(256) void gemm1_k(const float* __restrict__ A,
                                               const float* __restrict__ W,
                                               unsigned short* __restrict__ C, int N) {
    constexpr int AP = 132;
    __shared__ float As[26 * AP];
    __shared__ float Ws[26 * 128];
    const int tid  = threadIdx.x;
    const int wave = tid >> 6, lane = tid & 63;
    const int cg = (lane & 7) | ((wave & 1) << 3);
    const int rg = ((lane >> 3) & 7) | ((wave >> 1) << 3);
    const int row0 = blockIdx.x * 128;
    const int nrows = min(128, N - row0);

    for (int i = tid; i < 128 * 26; i += 256) {
        int r = i / 26, k = i - r * 26;
        As[k * AP + r] = (r < nrows) ? A[(size_t)row0 * 26 + i] : 0.f;
    }
    for (int i = tid; i < 26 * 128; i += 256) Ws[i] = W[i];

    float acc[8][8];
#pragma unroll
    for (int i = 0; i < 8; i++)
#pragma unroll
        for (int jj = 0; jj < 8; jj++) acc[i][jj] = 0.f;

    __syncthreads();
#pragma unroll 2
    for (int k = 0; k < 26; k++) {
        float4 a0 = *(const float4*)&As[k * AP + rg * 8];
        float4 a1 = *(const float4*)&As[k * AP + rg * 8 + 4];
        float4 w0 = *(const float4*)&Ws[k * 128 + cg * 8];
        float4 w1 = *(const float4*)&Ws[k * 128 + cg * 8 + 4];
        float a[8] = {a0.x, a0.y, a0.z, a0.w, a1.x, a1.y, a1.z, a1.w};
        float w[8] = {w0.x, w0.y, w0.z, w0.w, w1.x, w1.y, w1.z, w1.w};
#pragma unroll
        for (int i = 0; i < 8; i++)
#pragma unroll
            for (int jj = 0; jj < 8; jj++)
                acc[i][jj] = fmaf(a[i], w[jj], acc[i][jj]);
    }

#pragma unroll
    for (int i = 0; i < 8; i++) {
        int r = rg * 8 + i;
        if (r < nrows) {
            uint4 o;
            o.x = packbf(acc[i][0], acc[i][1]);
            o.y = packbf(acc[i][2], acc[i][3]);
            o.z = packbf(acc[i][4], acc[i][5]);
            o.w = packbf(acc[i][6], acc[i][7]);
            *(uint4*)&C[(size_t)(row0 + r) * 128 + cg * 8] = o;
        }
    }
}

// ---------------- fc: out[N,26](f32) = h[N,128](bf16) @ Wfc[128,26](f32) + bfc -----
__global__ __launch_bounds__(256) void gemmfc_k(const unsigned short* __restrict__ A,
                                                const float* __restrict__ W,
                                                const float* __restrict__ bias,
                                                float* __restrict__ C, int N) {
    constexpr int AP = 132;
    __shared__ float As[32 * AP];
    __shared__ float Ws[32 * 32];
    __shared__ float bs[32];
    const int tid  = threadIdx.x;
    const int wave = tid >> 6, lane = tid & 63;
    const int cg = lane & 7;
    const int rg = ((lane >> 3) & 7) | (wave << 3);
    const int row0 = blockIdx.x * 128;
    const int nrows = min(128, N - row0);

    if (tid < 32) bs[tid] = (tid < NCLASS) ? bias[tid] : 0.f;

    float acc[4][4];
#pragma unroll
    for (int i = 0; i < 4; i++)
#pragma unroll
        for (int jj = 0; jj < 4; jj++) acc[i][jj] = 0.f;

    for (int k0 = 0; k0 < 128; k0 += 32) {
        __syncthreads();
        for (int i = tid; i < 128 * 32; i += 256) {
            int r = i >> 5, k = i & 31;
            As[k * AP + r] = (r < nrows) ? bf2f(A[(size_t)(row0 + r) * 128 + k0 + k]) : 0.f;
        }
        for (int i = tid; i < 32 * 32; i += 256) {
            int k = i >> 5, c = i & 31;
            Ws[i] = (c < NCLASS) ? W[(size_t)(k0 + k) * NCLASS + c] : 0.f;
        }
        __syncthreads();
#pragma unroll 4
        for (int k = 0; k < 32; k++) {
            float4 a0 = *(const float4*)&As[k * AP + rg * 4];
            float4 w0 = *(const float4*)&Ws[k * 32 + cg * 4];
            float a[4] = {a0.x, a0.y, a0.z, a0.w};
            float w[4] = {w0.x, w0.y, w0.z, w0.w};
#pragma unroll
            for (int i = 0; i < 4; i++)
#pragma unroll
                for (int jj = 0; jj < 4; jj++)
                    acc[i][jj] = fmaf(a[i], w[jj], acc[i][jj]);
        }
    }

    const int c0 = cg * 4;
#pragma unroll
    for (int i = 0; i < 4; i++) {
        int r = rg * 4 + i;
        if (r < nrows && c0 < NCLASS) {
            float* dst = &C[(size_t)(row0 + r) * NCLASS + c0];
            if (c0 + 3 < NCLASS) {
                float4 v = {acc[i][0] + bs[c0], acc[i][1] + bs[c0 + 1],
                            acc[i][2] + bs[c0 + 2], acc[i][3] + bs[c0 + 3]};
                *(float4*)dst = v;
            } else {
                dst[0] = acc[i][0] + bs[c0];
                dst[1] = acc[i][1] + bs[c0 + 1];
            }
        }
    }
}

extern "C" void kernel_launch(void* const* d_in, const int* in_sizes, int n_in,
                              void* d_out, int out_size, void* d_ws, size_t ws_size,
                              hipStream_t stream) {
    const float* x   = (const float*)d_in[0];
    const int*   ei  = (const int*)d_in[1];
    const float* ew  = (const float*)d_in[2];
    const float* W1  = (const float*)d_in[3];
    const float* b1  = (const float*)d_in[4];
    const float* W2  = (const float*)d_in[5];
    const float* b2  = (const float*)d_in[6];
    const float* Wfc = (const float*)d_in[7];
    const float* bfc = (const float*)d_in[8];
    float* out = (float*)d_out;

    const int N = NNODES, E = NEDGES;
    const int* erow = ei;
    const int* ecol = ei + E;

    float* fws    = (float*)d_ws;
    float* dis    = fws;
    unsigned long long* pc = (unsigned long long*)(fws + 100000);
    int*   rowptr = (int*)(fws + 300000);
    int*   aux    = (int*)(fws + 400004);
    int*   cursor = (int*)(fws + 400516);
    uint2* meta   = (uint2*)(fws + 500516);
    unsigned short* wt16 = (unsigned short*)(fws + 1700516);
    unsigned short* hA16 = (unsigned short*)(fws + 1708708);
    unsigned short* hB16 = (unsigned short*)(fws + 8108708);

    const int gN = (N + 255) / 256;
    const int gE = (E + 255) / 256;
    const int g128 = (N + 127) / 128;  // 782
    const int gAgg = N / 8;            // 12500 (8 nodes per 256-thr block)

    // ---- gcn_norm + CSR build ----
    init_k<<<gN, 256, 0, stream>>>(pc, N);
    degcnt_k<<<gE, 256, 0, stream>>>(ecol, ew, pc, E);
    scan1_k<<<NBLK, 256, 0, stream>>>(pc, rowptr, aux, dis, N);
    scan2_k<<<1, 512, 0, stream>>>(aux, NBLK);
    scan3_k<<<NBLK, 256, 0, stream>>>(rowptr, pc, cursor, aux, N);
    place_k<<<gE, 256, 0, stream>>>(erow, ecol, ew, dis, rowptr, cursor, meta, E);
    wconv_k<<<64, 256, 0, stream>>>(W2, wt16);

    // ---- layer 1: x@W1 -> gather-agg(+b1, relu) ----
    gemm1_k<<<g128, 256, 0, stream>>>(x, W1, hA16, N);
    agg_k<<<gAgg, 256, 0, stream>>>(rowptr, meta, (const uint2*)hA16, dis, b1,
                                    (uint2*)hB16);

    // ---- layer 2: h@W2 (MFMA) -> gather-agg(+b2, relu) ----
    gemm2_k<<<g128, 256, 0, stream>>>(hB16, wt16, hA16, N);
    agg_k<<<gAgg, 256, 0, stream>>>(rowptr, meta, (const uint2*)hA16, dis, b2,
                                    (uint2*)hB16);

    // ---- fc ----
    gemmfc_k<<<g128, 256, 0, stream>>>(hB16, Wfc, bfc, out, N);
}

// Round 8
// 271.514 us; speedup vs baseline: 3.7617x; 1.1113x over previous
//
#include <hip/hip_runtime.h>

#define NNODES 100000
#define NEDGES 600000
#define NCLASS 26
#define HID    128

#define SHIFT  9
#define BCOLS  512                    // cols per bucket
#define NBKT   196                    // ceil(100000/512)
#define EPB    1024                   // edges per partition block
#define NBE    586                    // ceil(600000/1024)
#define NH     (NBKT * NBE)           // 114856 histogram cells

typedef __attribute__((ext_vector_type(8))) short bf16x8;
typedef __attribute__((ext_vector_type(4))) float f32x4;

__device__ inline unsigned short f2bf(float f) {  // RNE fp32->bf16
    unsigned int u = __float_as_uint(f);
    u += 0x7fffu + ((u >> 16) & 1u);
    return (unsigned short)(u >> 16);
}
__device__ inline float bf2f(unsigned short b) {
    return __uint_as_float((unsigned int)b << 16);
}
__device__ inline unsigned int packbf(float a, float b) {
    return (unsigned int)f2bf(a) | ((unsigned int)f2bf(b) << 16);
}
__device__ inline float2 bfpair(unsigned int p) {
    float2 r;
    r.x = __uint_as_float(p << 16);
    r.y = __uint_as_float(p & 0xffff0000u);
    return r;
}

// ---- pass A: per-block LDS histogram of edge->bucket ----
__global__ __launch_bounds__(256) void histA_k(const int* __restrict__ col,
                                               int* __restrict__ H) {
    __shared__ int h[NBKT];
    int t = threadIdx.x;
    for (int i = t; i < NBKT; i += 256) h[i] = 0;
    __syncthreads();
    int base = blockIdx.x * EPB;
#pragma unroll
    for (int u = 0; u < 4; u++) {
        int e = base + t + u * 256;
        if (e < NEDGES) atomicAdd(&h[col[e] >> SHIFT], 1);
    }
    __syncthreads();
    for (int i = t; i < NBKT; i += 256) H[i * NBE + blockIdx.x] = h[i];
}

// ---- scan of H (bucket-major): block-wise inclusive ----
__global__ void scanH1_k(const int* __restrict__ in, int* __restrict__ incl,
                         int* __restrict__ aux, int n) {
    __shared__ int s[256];
    int t = threadIdx.x, gi = blockIdx.x * 256 + t;
    s[t] = (gi < n) ? in[gi] : 0;
    __syncthreads();
    for (int off = 1; off < 256; off <<= 1) {
        int x = (t >= off) ? s[t - off] : 0;
        __syncthreads();
        s[t] += x;
        __syncthreads();
    }
    if (gi < n) incl[gi] = s[t];
    if (t == 255) aux[blockIdx.x] = s[255];
}

__global__ void scan2_k(int* __restrict__ aux, int n) {  // 1 block, 512 thr
    __shared__ int s[512];
    int t = threadIdx.x;
    s[t] = (t < n) ? aux[t] : 0;
    __syncthreads();
    for (int off = 1; off < 512; off <<= 1) {
        int x = (t >= off) ? s[t - off] : 0;
        __syncthreads();
        s[t] += x;
        __syncthreads();
    }
    if (t < n) aux[t] = s[t];
}

// incl -> exclusive in place (Hx[i] = incl[i] - H[i] + carry)
__global__ void scanx_k(const int* __restrict__ H, int* __restrict__ Hx,
                        const int* __restrict__ aux, int n) {
    int gi = blockIdx.x * 256 + threadIdx.x;
    if (gi < n) {
        int add = (blockIdx.x > 0) ? aux[blockIdx.x - 1] : 0;
        Hx[gi] = Hx[gi] - H[gi] + add;
    }
}

// ---- pass B: partition edges into bucket-contiguous storage ----
__global__ __launch_bounds__(256) void partB_k(const int* __restrict__ row,
                                               const int* __restrict__ col,
                                               const float* __restrict__ w,
                                               const int* __restrict__ Hx,
                                               uint2* __restrict__ rw,
                                               unsigned short* __restrict__ lc) {
    __shared__ int off[NBKT];
    __shared__ int cur[NBKT];
    int t = threadIdx.x;
    for (int i = t; i < NBKT; i += 256) {
        off[i] = Hx[i * NBE + blockIdx.x];
        cur[i] = 0;
    }
    __syncthreads();
    int base = blockIdx.x * EPB;
#pragma unroll
    for (int u = 0; u < 4; u++) {
        int e = base + t + u * 256;
        if (e < NEDGES) {
            int c = col[e], b = c >> SHIFT;
            int p = off[b] + atomicAdd(&cur[b], 1);
            rw[p] = make_uint2((unsigned int)row[e], __float_as_uint(w[e]));
            lc[p] = (unsigned short)(c & (BCOLS - 1));
        }
    }
}

// ---- F1: per-bucket degree/wsum (LDS atomics) -> dis + global rowptr ----
__global__ __launch_bounds__(256) void segbuild_k(const uint2* __restrict__ rw,
                                                  const unsigned short* __restrict__ lc,
                                                  const int* __restrict__ Hx,
                                                  int* __restrict__ rowptr,
                                                  float* __restrict__ dis) {
    __shared__ int   cnt[BCOLS];
    __shared__ float ws[BCOLS];
    __shared__ int   ps[256];
    int b = blockIdx.x, t = threadIdx.x;
    int c0 = b << SHIFT;
    int ncols = min(BCOLS, NNODES - c0);
    for (int i = t; i < BCOLS; i += 256) { cnt[i] = 0; ws[i] = 0.f; }
    __syncthreads();
    int s   = Hx[b * NBE];
    int eend = (b == NBKT - 1) ? NEDGES : Hx[(b + 1) * NBE];
    for (int e = s + t; e < eend; e += 256) {
        uint2 m = rw[e];
        int l = lc[e];
        atomicAdd(&cnt[l], 1);
        atomicAdd(&ws[l], __uint_as_float(m.y));
    }
    __syncthreads();
    for (int i = t; i < ncols; i += 256) dis[c0 + i] = rsqrtf(1.0f + ws[i]);
    // exclusive scan of cnt[0..512): 2 elems/thread + Hillis-Steele on partials
    int a0 = cnt[2 * t], a1 = cnt[2 * t + 1];
    ps[t] = a0 + a1;
    __syncthreads();
    for (int off = 1; off < 256; off <<= 1) {
        int x = (t >= off) ? ps[t - off] : 0;
        __syncthreads();
        ps[t] += x;
        __syncthreads();
    }
    int ex = (t > 0) ? ps[t - 1] : 0;
    if (2 * t     < ncols) rowptr[c0 + 2 * t]     = s + ex;
    if (2 * t + 1 < ncols) rowptr[c0 + 2 * t + 1] = s + ex + a0;
    if (b == NBKT - 1 && t == 0) rowptr[NNODES] = NEDGES;
}

// ---- F2: per-bucket placement (LDS cursors), meta = (src, norm) ----
__global__ __launch_bounds__(256) void segplace_k(const uint2* __restrict__ rw,
                                                  const unsigned short* __restrict__ lc,
                                                  const int* __restrict__ Hx,
                                                  const int* __restrict__ rowptr,
                                                  const float* __restrict__ dis,
                                                  uint2* __restrict__ meta) {
    __shared__ int   rpl[BCOLS];
    __shared__ int   cur[BCOLS];
    __shared__ float dcs[BCOLS];
    int b = blockIdx.x, t = threadIdx.x;
    int c0 = b << SHIFT;
    int ncols = min(BCOLS, NNODES - c0);
    for (int i = t; i < BCOLS; i += 256) {
        cur[i] = 0;
        if (i < ncols) { rpl[i] = rowptr[c0 + i]; dcs[i] = dis[c0 + i]; }
    }
    __syncthreads();
    int s    = Hx[b * NBE];
    int eend = (b == NBKT - 1) ? NEDGES : Hx[(b + 1) * NBE];
    for (int e = s + t; e < eend; e += 256) {
        uint2 m = rw[e];
        int l = lc[e];
        int pos = rpl[l] + atomicAdd(&cur[l], 1);
        float v = dis[m.x] * __uint_as_float(m.y) * dcs[l];
        meta[pos] = make_uint2(m.x, __float_as_uint(v));
    }
}

// ---- W2 -> bf16 transposed: Wt[c][k] = W[k][c] ----
__global__ void wconv_k(const float* __restrict__ W, unsigned short* __restrict__ Wt) {
    int idx = blockIdx.x * 256 + threadIdx.x;
    if (idx < 128 * 128) {
        int c = idx >> 7, k = idx & 127;
        Wt[c * 128 + k] = f2bf(W[k * 128 + c]);
    }
}

// ---- gather-aggregate: 2 nodes/wave, 32 lanes/node, uint2 (4 feats)/lane ----
__global__ __launch_bounds__(256) void agg_k(const int* __restrict__ rowptr,
                                             const uint2* __restrict__ meta,
                                             const uint2* __restrict__ h,
                                             const float* __restrict__ dis,
                                             const float* __restrict__ bias,
                                             uint2* __restrict__ out) {
    int node = blockIdx.x * 8 + (threadIdx.x >> 5);
    if (node >= NNODES) return;
    int lane = threadIdx.x & 31;

    float d = dis[node];
    uint2 hcu = h[node * 32 + lane];
    float2 h0 = bfpair(hcu.x), h1 = bfpair(hcu.y);
    float4 acc;
    acc.x = d * d * h0.x; acc.y = d * d * h0.y;
    acc.z = d * d * h1.x; acc.w = d * d * h1.y;

    int j = rowptr[node], jend = rowptr[node + 1];
    for (; j + 3 < jend; j += 4) {
        uint2 m0 = meta[j],     m1 = meta[j + 1];
        uint2 m2 = meta[j + 2], m3 = meta[j + 3];
        uint2 g0 = h[m0.x * 32 + lane];
        uint2 g1 = h[m1.x * 32 + lane];
        uint2 g2 = h[m2.x * 32 + lane];
        uint2 g3 = h[m3.x * 32 + lane];
        float v0 = __uint_as_float(m0.y), v1 = __uint_as_float(m1.y);
        float v2 = __uint_as_float(m2.y), v3 = __uint_as_float(m3.y);
        float2 a, b;
        a = bfpair(g0.x); b = bfpair(g0.y);
        acc.x = fmaf(v0, a.x, acc.x); acc.y = fmaf(v0, a.y, acc.y);
        acc.z = fmaf(v0, b.x, acc.z); acc.w = fmaf(v0, b.y, acc.w);
        a = bfpair(g1.x); b = bfpair(g1.y);
        acc.x = fmaf(v1, a.x, acc.x); acc.y = fmaf(v1, a.y, acc.y);
        acc.z = fmaf(v1, b.x, acc.z); acc.w = fmaf(v1, b.y, acc.w);
        a = bfpair(g2.x); b = bfpair(g2.y);
        acc.x = fmaf(v2, a.x, acc.x); acc.y = fmaf(v2, a.y, acc.y);
        acc.z = fmaf(v2, b.x, acc.z); acc.w = fmaf(v2, b.y, acc.w);
        a = bfpair(g3.x); b = bfpair(g3.y);
        acc.x = fmaf(v3, a.x, acc.x); acc.y = fmaf(v3, a.y, acc.y);
        acc.z = fmaf(v3, b.x, acc.z); acc.w = fmaf(v3, b.y, acc.w);
    }
    for (; j < jend; j++) {
        uint2 m = meta[j];
        float v = __uint_as_float(m.y);
        uint2 g = h[m.x * 32 + lane];
        float2 a = bfpair(g.x), b = bfpair(g.y);
        acc.x = fmaf(v, a.x, acc.x); acc.y = fmaf(v, a.y, acc.y);
        acc.z = fmaf(v, b.x, acc.z); acc.w = fmaf(v, b.y, acc.w);
    }

    float4 bv = ((const float4*)bias)[lane];
    acc.x = fmaxf(acc.x + bv.x, 0.f);
    acc.y = fmaxf(acc.y + bv.y, 0.f);
    acc.z = fmaxf(acc.z + bv.z, 0.f);
    acc.w = fmaxf(acc.w + bv.w, 0.f);
    out[node * 32 + lane] = make_uint2(packbf(acc.x, acc.y), packbf(acc.z, acc.w));
}

// ---- GEMM2 (MFMA bf16): C[N,128] = A[N,128] @ W2, bf16 in/out ----
__global__ __launch_bounds__(256) void gemm2_k(const unsigned short* __restrict__ A,
                                               const unsigned short* __restrict__ Wt,
                                               unsigned short* __restrict__ C, int N) {
    __shared__ unsigned short As[128 * 72];
    __shared__ unsigned short Ws[128 * 72];
    const int tid  = threadIdx.x;
    const int wave = tid >> 6, lane = tid & 63;
    const int quad = lane >> 4, l16 = lane & 15;
    const int wm = wave >> 1, wn = wave & 1;
    const int row0 = blockIdx.x * 128;

    f32x4 acc[4][4];
#pragma unroll
    for (int i = 0; i < 4; i++)
#pragma unroll
        for (int j = 0; j < 4; j++) acc[i][j] = (f32x4)0.f;

    for (int c = 0; c < 2; c++) {
        const int k0g = c * 64;
        __syncthreads();
#pragma unroll
        for (int j = 0; j < 4; j++) {
            int idx = tid + j * 256;
            int r = idx >> 3, ku = idx & 7;
            uint4 va = make_uint4(0u, 0u, 0u, 0u);
            if (row0 + r < N)
                va = *(const uint4*)&A[(size_t)(row0 + r) * 128 + k0g + ku * 8];
            *(uint4*)&As[r * 72 + ku * 8] = va;
            uint4 vw = *(const uint4*)&Wt[(size_t)r * 128 + k0g + ku * 8];
            *(uint4*)&Ws[r * 72 + ku * 8] = vw;
        }
        __syncthreads();
#pragma unroll
        for (int kc = 0; kc < 2; kc++) {
            const int kl = kc * 32 + quad * 8;
            bf16x8 af[4], bfr[4];
#pragma unroll
            for (int t = 0; t < 4; t++) {
                af[t]  = *(const bf16x8*)&As[(wm * 64 + t * 16 + l16) * 72 + kl];
                bfr[t] = *(const bf16x8*)&Ws[(wn * 64 + t * 16 + l16) * 72 + kl];
            }
#pragma unroll
            for (int tm = 0; tm < 4; tm++)
#pragma unroll
                for (int tn = 0; tn < 4; tn++)
                    acc[tm][tn] = __builtin_amdgcn_mfma_f32_16x16x32_bf16(
                        af[tm], bfr[tn], acc[tm][tn], 0, 0, 0);
        }
    }

#pragma unroll
    for (int tm = 0; tm < 4; tm++) {
        const int rbase = row0 + wm * 64 + tm * 16 + quad * 4;
#pragma unroll
        for (int tn = 0; tn < 4; tn++) {
            const int col = wn * 64 + tn * 16 + l16;
#pragma unroll
            for (int r = 0; r < 4; r++) {
                if (rbase + r < N)
                    C[(size_t)(rbase + r) * 128 + col] = f2bf(acc[tm][tn][r]);
            }
        }
    }
}

// ---- GEMM1: C[N,128](bf16) = x[N,26](f32) @ W1[26,128](f32) ----
__global__ __launch_bounds__(256) void gemm1_k(const float* __restrict__ A,
                                               const float* __restrict__ W,
                                               unsigned short* __restrict__ C, int N) {
    constexpr int AP = 132;
    __shared__ float As[26 * AP];
    __shared__ float Ws[26 * 128];
    const int tid  = threadIdx.x;
    const int wave = tid >> 6, lane = tid & 63;
    const int cg = (lane & 7) | ((wave & 1) << 3);
    const int rg = ((lane >> 3) & 7) | ((wave >> 1) << 3);
    const int row0 = blockIdx.x * 128;
    const int nrows = min(128, N - row0);

    for (int i = tid; i < 128 * 26; i += 256) {
        int r = i / 26, k = i - r * 26;
        As[k * AP + r] = (r < nrows) ? A[(size_t)row0 * 26 + i] : 0.f;
    }
    for (int i = tid; i < 26 * 128; i += 256) Ws[i] = W[i];

    float acc[8][8];
#pragma unroll
    for (int i = 0; i < 8; i++)
#pragma unroll
        for (int jj = 0; jj < 8; jj++) acc[i][jj] = 0.f;

    __syncthreads();
#pragma unroll 2
    for (int k = 0; k < 26; k++) {
        float4 a0 = *(const float4*)&As[k * AP + rg * 8];
        float4 a1 = *(const float4*)&As[k * AP + rg * 8 + 4];
        float4 w0 = *(const float4*)&Ws[k * 128 + cg * 8];
        float4 w1 = *(const float4*)&Ws[k * 128 + cg * 8 + 4];
        float a[8] = {a0.x, a0.y, a0.z, a0.w, a1.x, a1.y, a1.z, a1.w};
        float w[8] = {w0.x, w0.y, w0.z, w0.w, w1.x, w1.y, w1.z, w1.w};
#pragma unroll
        for (int i = 0; i < 8; i++)
#pragma unroll
            for (int jj = 0; jj < 8; jj++)
                acc[i][jj] = fmaf(a[i], w[jj], acc[i][jj]);
    }

#pragma unroll
    for (int i = 0; i < 8; i++) {
        int r = rg * 8 + i;
        if (r < nrows) {
            uint4 o;
            o.x = packbf(acc[i][0], acc[i][1]);
            o.y = packbf(acc[i][2], acc[i][3]);
            o.z = packbf(acc[i][4], acc[i][5]);
            o.w = packbf(acc[i][6], acc[i][7]);
            *(uint4*)&C[(size_t)(row0 + r) * 128 + cg * 8] = o;
        }
    }
}

// ---- fc: out[N,26](f32) = h[N,128](bf16) @ Wfc[128,26](f32) + bfc ----
__global__ __launch_bounds__(256) void gemmfc_k(const unsigned short* __restrict__ A,
                                                const float* __restrict__ W,
                                                const float* __restrict__ bias,
                                                float* __restrict__ C, int N) {
    constexpr int AP = 132;
    __shared__ float As[32 * AP];
    __shared__ float Ws[32 * 32];
    __shared__ float bs[32];
    const int tid  = threadIdx.x;
    const int wave = tid >> 6, lane = tid & 63;
    const int cg = lane & 7;
    const int rg = ((lane >> 3) & 7) | (wave << 3);
    const int row0 = blockIdx.x * 128;
    const int nrows = min(128, N - row0);

    if (tid < 32) bs[tid] = (tid < NCLASS) ? bias[tid] : 0.f;

    float acc[4][4];
#pragma unroll
    for (int i = 0; i < 4; i++)
#pragma unroll
        for (int jj = 0; jj < 4; jj++) acc[i][jj] = 0.f;

    for (int k0 = 0; k0 < 128; k0 += 32) {
        __syncthreads();
        for (int i = tid; i < 128 * 32; i += 256) {
            int r = i >> 5, k = i & 31;
            As[k * AP + r] = (r < nrows) ? bf2f(A[(size_t)(row0 + r) * 128 + k0 + k]) : 0.f;
        }
        for (int i = tid; i < 32 * 32; i += 256) {
            int k = i >> 5, c = i & 31;
            Ws[i] = (c < NCLASS) ? W[(size_t)(k0 + k) * NCLASS + c] : 0.f;
        }
        __syncthreads();
#pragma unroll 4
        for (int k = 0; k < 32; k++) {
            float4 a0 = *(const float4*)&As[k * AP + rg * 4];
            float4 w0 = *(const float4*)&Ws[k * 32 + cg * 4];
            float a[4] = {a0.x, a0.y, a0.z, a0.w};
            float w[4] = {w0.x, w0.y, w0.z, w0.w};
#pragma unroll
            for (int i = 0; i < 4; i++)
#pragma unroll
                for (int jj = 0; jj < 4; jj++)
                    acc[i][jj] = fmaf(a[i], w[jj], acc[i][jj]);
        }
    }

    const int c0 = cg * 4;
#pragma unroll
    for (int i = 0; i < 4; i++) {
        int r = rg * 4 + i;
        if (r < nrows && c0 < NCLASS) {
            float* dst = &C[(size_t)(row0 + r) * NCLASS + c0];
            if (c0 + 3 < NCLASS) {
                float4 v = {acc[i][0] + bs[c0], acc[i][1] + bs[c0 + 1],
                            acc[i][2] + bs[c0 + 2], acc[i][3] + bs[c0 + 3]};
                *(float4*)dst = v;
            } else {
                dst[0] = acc[i][0] + bs[c0];
                dst[1] = acc[i][1] + bs[c0 + 1];
            }
        }
    }
}

extern "C" void kernel_launch(void* const* d_in, const int* in_sizes, int n_in,
                              void* d_out, int out_size, void* d_ws, size_t ws_size,
                              hipStream_t stream) {
    const float* x   = (const float*)d_in[0];
    const int*   ei  = (const int*)d_in[1];
    const float* ew  = (const float*)d_in[2];
    const float* W1  = (const float*)d_in[3];
    const float* b1  = (const float*)d_in[4];
    const float* W2  = (const float*)d_in[5];
    const float* b2  = (const float*)d_in[6];
    const float* Wfc = (const float*)d_in[7];
    const float* bfc = (const float*)d_in[8];
    float* out = (float*)d_out;

    const int N = NNODES;
    const int* erow = ei;
    const int* ecol = ei + NEDGES;

    // ws layout (float-unit offsets):
    // dis[100000] @0 | rowptr[100001] @100000 | H[114856] @200004 | Hx[114856] @314860
    // aux[512] @429716 | rw[600000 uint2] @430228 | lc[600000 u16] @1630228
    // meta[600000 uint2] @1930228 | wt16 @3130228 | hA16 @3138420 | hB16 @9538420
    float* fws    = (float*)d_ws;
    float* dis    = fws;
    int*   rowptr = (int*)(fws + 100000);
    int*   H      = (int*)(fws + 200004);
    int*   Hx     = (int*)(fws + 314860);
    int*   aux    = (int*)(fws + 429716);
    uint2* rw     = (uint2*)(fws + 430228);
    unsigned short* lc = (unsigned short*)(fws + 1630228);
    uint2* meta   = (uint2*)(fws + 1930228);
    unsigned short* wt16 = (unsigned short*)(fws + 3130228);
    unsigned short* hA16 = (unsigned short*)(fws + 3138420);
    unsigned short* hB16 = (unsigned short*)(fws + 9538420);

    const int gScan = (NH + 255) / 256;  // 449
    const int g128  = (N + 127) / 128;   // 782
    const int gAgg  = N / 8;             // 12500

    // ---- CSR build: bucket partition + LDS-local counting sort ----
    histA_k<<<NBE, 256, 0, stream>>>(ecol, H);
    scanH1_k<<<gScan, 256, 0, stream>>>(H, Hx, aux, NH);
    scan2_k<<<1, 512, 0, stream>>>(aux, gScan);
    scanx_k<<<gScan, 256, 0, stream>>>(H, Hx, aux, NH);
    partB_k<<<NBE, 256, 0, stream>>>(erow, ecol, ew, Hx, rw, lc);
    segbuild_k<<<NBKT, 256, 0, stream>>>(rw, lc, Hx, rowptr, dis);
    segplace_k<<<NBKT, 256, 0, stream>>>(rw, lc, Hx, rowptr, dis, meta);
    wconv_k<<<64, 256, 0, stream>>>(W2, wt16);

    // ---- layer 1: x@W1 -> gather-agg(+b1, relu) ----
    gemm1_k<<<g128, 256, 0, stream>>>(x, W1, hA16, N);
    agg_k<<<gAgg, 256, 0, stream>>>(rowptr, meta, (const uint2*)hA16, dis, b1,
                                    (uint2*)hB16);

    // ---- layer 2: h@W2 (MFMA) -> gather-agg(+b2, relu) ----
    gemm2_k<<<g128, 256, 0, stream>>>(hB16, wt16, hA16, N);
    agg_k<<<gAgg, 256, 0, stream>>>(rowptr, meta, (const uint2*)hA16, dis, b2,
                                    (uint2*)hB16);

    // ---- fc ----
    gemmfc_k<<<g128, 256, 0, stream>>>(hB16, Wfc, bfc, out, N);
}

// Round 9
// 247.136 us; speedup vs baseline: 4.1327x; 1.0986x over previous
//
#include <hip/hip_runtime.h>

#define NNODES 100000
#define NEDGES 600000
#define NCLASS 26
#define HID    128

#define SHIFT  9
#define BCOLS  512                    // cols per bucket
#define NBKT   196                    // ceil(100000/512)
#define EPB    1024                   // edges per partition block
#define NBE    586                    // ceil(600000/1024)
#define NH     (NBKT * NBE)           // 114856 histogram cells

typedef __attribute__((ext_vector_type(8))) short bf16x8;
typedef __attribute__((ext_vector_type(4))) float f32x4;

__device__ inline unsigned short f2bf(float f) {  // RNE fp32->bf16
    unsigned int u = __float_as_uint(f);
    u += 0x7fffu + ((u >> 16) & 1u);
    return (unsigned short)(u >> 16);
}
__device__ inline float bf2f(unsigned short b) {
    return __uint_as_float((unsigned int)b << 16);
}
__device__ inline unsigned int packbf(float a, float b) {
    return (unsigned int)f2bf(a) | ((unsigned int)f2bf(b) << 16);
}
__device__ inline float2 bfpair(unsigned int p) {
    float2 r;
    r.x = __uint_as_float(p << 16);
    r.y = __uint_as_float(p & 0xffff0000u);
    return r;
}

// ---- pass A: per-block LDS histogram of edge->bucket ----
__global__ __launch_bounds__(256) void histA_k(const int* __restrict__ col,
                                               int* __restrict__ H) {
    __shared__ int h[NBKT];
    int t = threadIdx.x;
    for (int i = t; i < NBKT; i += 256) h[i] = 0;
    __syncthreads();
    int base = blockIdx.x * EPB;
#pragma unroll
    for (int u = 0; u < 4; u++) {
        int e = base + t + u * 256;
        if (e < NEDGES) atomicAdd(&h[col[e] >> SHIFT], 1);
    }
    __syncthreads();
    for (int i = t; i < NBKT; i += 256) H[i * NBE + blockIdx.x] = h[i];
}

__global__ void scanH1_k(const int* __restrict__ in, int* __restrict__ incl,
                         int* __restrict__ aux, int n) {
    __shared__ int s[256];
    int t = threadIdx.x, gi = blockIdx.x * 256 + t;
    s[t] = (gi < n) ? in[gi] : 0;
    __syncthreads();
    for (int off = 1; off < 256; off <<= 1) {
        int x = (t >= off) ? s[t - off] : 0;
        __syncthreads();
        s[t] += x;
        __syncthreads();
    }
    if (gi < n) incl[gi] = s[t];
    if (t == 255) aux[blockIdx.x] = s[255];
}

__global__ void scan2_k(int* __restrict__ aux, int n) {  // 1 block, 512 thr
    __shared__ int s[512];
    int t = threadIdx.x;
    s[t] = (t < n) ? aux[t] : 0;
    __syncthreads();
    for (int off = 1; off < 512; off <<= 1) {
        int x = (t >= off) ? s[t - off] : 0;
        __syncthreads();
        s[t] += x;
        __syncthreads();
    }
    if (t < n) aux[t] = s[t];
}

__global__ void scanx_k(const int* __restrict__ H, int* __restrict__ Hx,
                        const int* __restrict__ aux, int n) {
    int gi = blockIdx.x * 256 + threadIdx.x;
    if (gi < n) {
        int add = (blockIdx.x > 0) ? aux[blockIdx.x - 1] : 0;
        Hx[gi] = Hx[gi] - H[gi] + add;
    }
}

// ---- pass B: partition edges into bucket-contiguous storage ----
__global__ __launch_bounds__(256) void partB_k(const int* __restrict__ row,
                                               const int* __restrict__ col,
                                               const float* __restrict__ w,
                                               const int* __restrict__ Hx,
                                               uint2* __restrict__ rw,
                                               unsigned short* __restrict__ lc) {
    __shared__ int off[NBKT];
    __shared__ int cur[NBKT];
    int t = threadIdx.x;
    for (int i = t; i < NBKT; i += 256) {
        off[i] = Hx[i * NBE + blockIdx.x];
        cur[i] = 0;
    }
    __syncthreads();
    int base = blockIdx.x * EPB;
#pragma unroll
    for (int u = 0; u < 4; u++) {
        int e = base + t + u * 256;
        if (e < NEDGES) {
            int c = col[e], b = c >> SHIFT;
            int p = off[b] + atomicAdd(&cur[b], 1);
            rw[p] = make_uint2((unsigned int)row[e], __float_as_uint(w[e]));
            lc[p] = (unsigned short)(c & (BCOLS - 1));
        }
    }
}

// ---- F1: per-bucket degree/wsum (LDS atomics) -> dis + global rowptr ----
__global__ __launch_bounds__(256) void segbuild_k(const uint2* __restrict__ rw,
                                                  const unsigned short* __restrict__ lc,
                                                  const int* __restrict__ Hx,
                                                  int* __restrict__ rowptr,
                                                  float* __restrict__ dis) {
    __shared__ int   cnt[BCOLS];
    __shared__ float ws[BCOLS];
    __shared__ int   ps[256];
    int b = blockIdx.x, t = threadIdx.x;
    int c0 = b << SHIFT;
    int ncols = min(BCOLS, NNODES - c0);
    for (int i = t; i < BCOLS; i += 256) { cnt[i] = 0; ws[i] = 0.f; }
    __syncthreads();
    int s   = Hx[b * NBE];
    int eend = (b == NBKT - 1) ? NEDGES : Hx[(b + 1) * NBE];
    for (int e = s + t; e < eend; e += 256) {
        uint2 m = rw[e];
        int l = lc[e];
        atomicAdd(&cnt[l], 1);
        atomicAdd(&ws[l], __uint_as_float(m.y));
    }
    __syncthreads();
    for (int i = t; i < ncols; i += 256) dis[c0 + i] = rsqrtf(1.0f + ws[i]);
    int a0 = cnt[2 * t], a1 = cnt[2 * t + 1];
    ps[t] = a0 + a1;
    __syncthreads();
    for (int off = 1; off < 256; off <<= 1) {
        int x = (t >= off) ? ps[t - off] : 0;
        __syncthreads();
        ps[t] += x;
        __syncthreads();
    }
    int ex = (t > 0) ? ps[t - 1] : 0;
    if (2 * t     < ncols) rowptr[c0 + 2 * t]     = s + ex;
    if (2 * t + 1 < ncols) rowptr[c0 + 2 * t + 1] = s + ex + a0;
    if (b == NBKT - 1 && t == 0) rowptr[NNODES] = NEDGES;
}

// ---- F2: per-bucket placement (LDS cursors), meta = (src, norm) ----
__global__ __launch_bounds__(256) void segplace_k(const uint2* __restrict__ rw,
                                                  const unsigned short* __restrict__ lc,
                                                  const int* __restrict__ Hx,
                                                  const int* __restrict__ rowptr,
                                                  const float* __restrict__ dis,
                                                  uint2* __restrict__ meta) {
    __shared__ int   rpl[BCOLS];
    __shared__ int   cur[BCOLS];
    __shared__ float dcs[BCOLS];
    int b = blockIdx.x, t = threadIdx.x;
    int c0 = b << SHIFT;
    int ncols = min(BCOLS, NNODES - c0);
    for (int i = t; i < BCOLS; i += 256) {
        cur[i] = 0;
        if (i < ncols) { rpl[i] = rowptr[c0 + i]; dcs[i] = dis[c0 + i]; }
    }
    __syncthreads();
    int s    = Hx[b * NBE];
    int eend = (b == NBKT - 1) ? NEDGES : Hx[(b + 1) * NBE];
    for (int e = s + t; e < eend; e += 256) {
        uint2 m = rw[e];
        int l = lc[e];
        int pos = rpl[l] + atomicAdd(&cur[l], 1);
        float v = dis[m.x] * __uint_as_float(m.y) * dcs[l];
        meta[pos] = make_uint2(m.x, __float_as_uint(v));
    }
}

// ---- W2 -> bf16 transposed: Wt[c][k] = W[k][c] ----
__global__ void wconv_k(const float* __restrict__ W, unsigned short* __restrict__ Wt) {
    int idx = blockIdx.x * 256 + threadIdx.x;
    if (idx < 128 * 128) {
        int c = idx >> 7, k = idx & 127;
        Wt[c * 128 + k] = f2bf(W[k * 128 + c]);
    }
}

// ---- W1[26,128] -> bf16 transposed+padded: W1t[c][k], k 26..31 = 0 ----
__global__ void w1conv_k(const float* __restrict__ W, unsigned short* __restrict__ Wt) {
    int idx = blockIdx.x * 256 + threadIdx.x;
    if (idx < 128 * 32) {
        int c = idx >> 5, k = idx & 31;
        Wt[c * 32 + k] = (k < NCLASS) ? f2bf(W[k * 128 + c]) : (unsigned short)0;
    }
}

// ---- x[N,26] f32 -> xp[N,32] bf16 (padded, packed as 16 uints/row) ----
__global__ void padx_k(const float* __restrict__ x, unsigned int* __restrict__ xp) {
    int i = blockIdx.x * 256 + threadIdx.x;
    if (i < NNODES * 16) {
        int r = i >> 4, u = i & 15;
        int f0 = u * 2;
        float a = (f0     < NCLASS) ? x[r * NCLASS + f0]     : 0.f;
        float b = (f0 + 1 < NCLASS) ? x[r * NCLASS + f0 + 1] : 0.f;
        xp[i] = packbf(a, b);
    }
}

// ---- agg in 26(->32)-dim: 4 nodes/wave, 16 lanes/node, 64B row gathers ----
// aggx[node] = d^2 * xp[node] + sum_e norm * xp[src]   (no bias/relu -- pre-W1)
__global__ __launch_bounds__(256) void agg26_k(const int* __restrict__ rowptr,
                                               const uint2* __restrict__ meta,
                                               const unsigned int* __restrict__ xp,
                                               const float* __restrict__ dis,
                                               unsigned int* __restrict__ aggx) {
    int node = blockIdx.x * 16 + (threadIdx.x >> 4);   // N divisible by 16
    int lane = threadIdx.x & 15;

    float d = dis[node];
    float2 acc = bfpair(xp[node * 16 + lane]);
    acc.x *= d * d; acc.y *= d * d;

    int j = rowptr[node], jend = rowptr[node + 1];
    for (; j + 3 < jend; j += 4) {
        uint2 m0 = meta[j],     m1 = meta[j + 1];
        uint2 m2 = meta[j + 2], m3 = meta[j + 3];
        unsigned int g0 = xp[m0.x * 16 + lane];
        unsigned int g1 = xp[m1.x * 16 + lane];
        unsigned int g2 = xp[m2.x * 16 + lane];
        unsigned int g3 = xp[m3.x * 16 + lane];
        float v0 = __uint_as_float(m0.y), v1 = __uint_as_float(m1.y);
        float v2 = __uint_as_float(m2.y), v3 = __uint_as_float(m3.y);
        float2 a;
        a = bfpair(g0); acc.x = fmaf(v0, a.x, acc.x); acc.y = fmaf(v0, a.y, acc.y);
        a = bfpair(g1); acc.x = fmaf(v1, a.x, acc.x); acc.y = fmaf(v1, a.y, acc.y);
        a = bfpair(g2); acc.x = fmaf(v2, a.x, acc.x); acc.y = fmaf(v2, a.y, acc.y);
        a = bfpair(g3); acc.x = fmaf(v3, a.x, acc.x); acc.y = fmaf(v3, a.y, acc.y);
    }
    for (; j < jend; j++) {
        uint2 m = meta[j];
        float v = __uint_as_float(m.y);
        float2 a = bfpair(xp[m.x * 16 + lane]);
        acc.x = fmaf(v, a.x, acc.x); acc.y = fmaf(v, a.y, acc.y);
    }
    aggx[node * 16 + lane] = packbf(acc.x, acc.y);
}

// ---- gemm1 (MFMA, K=32 single step): h1 = relu(aggx @ W1 + b1), bf16 out ----
// A frag direct from global (aggx row-major [N,32]); B frags (W1t) in registers.
__global__ __launch_bounds__(256) void gemm1_k(const unsigned short* __restrict__ aggx,
                                               const unsigned short* __restrict__ w1t,
                                               const float* __restrict__ bias,
                                               unsigned short* __restrict__ C, int N) {
    const int tid  = threadIdx.x;
    const int wv = tid >> 6, lane = tid & 63;
    const int quad = lane >> 4, l16 = lane & 15;
    const int row0 = blockIdx.x * 64 + wv * 16;

    bf16x8 bf[8];
#pragma unroll
    for (int n = 0; n < 8; n++)
        bf[n] = *(const bf16x8*)&w1t[(n * 16 + l16) * 32 + quad * 8];

    bf16x8 af = (bf16x8)(short)0;
    int arow = row0 + l16;
    if (arow < N) af = *(const bf16x8*)&aggx[(size_t)arow * 32 + quad * 8];

#pragma unroll
    for (int n = 0; n < 8; n++) {
        f32x4 acc = __builtin_amdgcn_mfma_f32_16x16x32_bf16(af, bf[n], (f32x4)0.f, 0, 0, 0);
        int col = n * 16 + l16;
        float bv = bias[col];
        int r0 = row0 + quad * 4;
#pragma unroll
        for (int r = 0; r < 4; r++) {
            if (r0 + r < N)
                C[(size_t)(r0 + r) * 128 + col] = f2bf(fmaxf(acc[r] + bv, 0.f));
        }
    }
}

// ---- gather-aggregate 128-dim: 2 nodes/wave, 32 lanes/node, +bias+relu ----
__global__ __launch_bounds__(256) void agg_k(const int* __restrict__ rowptr,
                                             const uint2* __restrict__ meta,
                                             const uint2* __restrict__ h,
                                             const float* __restrict__ dis,
                                             const float* __restrict__ bias,
                                             uint2* __restrict__ out) {
    int node = blockIdx.x * 8 + (threadIdx.x >> 5);
    if (node >= NNODES) return;
    int lane = threadIdx.x & 31;

    float d = dis[node];
    uint2 hcu = h[node * 32 + lane];
    float2 h0 = bfpair(hcu.x), h1 = bfpair(hcu.y);
    float4 acc;
    acc.x = d * d * h0.x; acc.y = d * d * h0.y;
    acc.z = d * d * h1.x; acc.w = d * d * h1.y;

    int j = rowptr[node], jend = rowptr[node + 1];
    for (; j + 3 < jend; j += 4) {
        uint2 m0 = meta[j],     m1 = meta[j + 1];
        uint2 m2 = meta[j + 2], m3 = meta[j + 3];
        uint2 g0 = h[m0.x * 32 + lane];
        uint2 g1 = h[m1.x * 32 + lane];
        uint2 g2 = h[m2.x * 32 + lane];
        uint2 g3 = h[m3.x * 32 + lane];
        float v0 = __uint_as_float(m0.y), v1 = __uint_as_float(m1.y);
        float v2 = __uint_as_float(m2.y), v3 = __uint_as_float(m3.y);
        float2 a, b;
        a = bfpair(g0.x); b = bfpair(g0.y);
        acc.x = fmaf(v0, a.x, acc.x); acc.y = fmaf(v0, a.y, acc.y);
        acc.z = fmaf(v0, b.x, acc.z); acc.w = fmaf(v0, b.y, acc.w);
        a = bfpair(g1.x); b = bfpair(g1.y);
        acc.x = fmaf(v1, a.x, acc.x); acc.y = fmaf(v1, a.y, acc.y);
        acc.z = fmaf(v1, b.x, acc.z); acc.w = fmaf(v1, b.y, acc.w);
        a = bfpair(g2.x); b = bfpair(g2.y);
        acc.x = fmaf(v2, a.x, acc.x); acc.y = fmaf(v2, a.y, acc.y);
        acc.z = fmaf(v2, b.x, acc.z); acc.w = fmaf(v2, b.y, acc.w);
        a = bfpair(g3.x); b = bfpair(g3.y);
        acc.x = fmaf(v3, a.x, acc.x); acc.y = fmaf(v3, a.y, acc.y);
        acc.z = fmaf(v3, b.x, acc.z); acc.w = fmaf(v3, b.y, acc.w);
    }
    for (; j < jend; j++) {
        uint2 m = meta[j];
        float v = __uint_as_float(m.y);
        uint2 g = h[m.x * 32 + lane];
        float2 a = bfpair(g.x), b = bfpair(g.y);
        acc.x = fmaf(v, a.x, acc.x); acc.y = fmaf(v, a.y, acc.y);
        acc.z = fmaf(v, b.x, acc.z); acc.w = fmaf(v, b.y, acc.w);
    }

    float4 bv = ((const float4*)bias)[lane];
    acc.x = fmaxf(acc.x + bv.x, 0.f);
    acc.y = fmaxf(acc.y + bv.y, 0.f);
    acc.z = fmaxf(acc.z + bv.z, 0.f);
    acc.w = fmaxf(acc.w + bv.w, 0.f);
    out[node * 32 + lane] = make_uint2(packbf(acc.x, acc.y), packbf(acc.z, acc.w));
}

// ---- GEMM2 (MFMA bf16): C[N,128] = A[N,128] @ W2, bf16 in/out ----
__global__ __launch_bounds__(256) void gemm2_k(const unsigned short* __restrict__ A,
                                               const unsigned short* __restrict__ Wt,
                                               unsigned short* __restrict__ C, int N) {
    __shared__ unsigned short As[128 * 72];
    __shared__ unsigned short Ws[128 * 72];
    const int tid  = threadIdx.x;
    const int wave = tid >> 6, lane = tid & 63;
    const int quad = lane >> 4, l16 = lane & 15;
    const int wm = wave >> 1, wn = wave & 1;
    const int row0 = blockIdx.x * 128;

    f32x4 acc[4][4];
#pragma unroll
    for (int i = 0; i < 4; i++)
#pragma unroll
        for (int j = 0; j < 4; j++) acc[i][j] = (f32x4)0.f;

    for (int c = 0; c < 2; c++) {
        const int k0g = c * 64;
        __syncthreads();
#pragma unroll
        for (int j = 0; j < 4; j++) {
            int idx = tid + j * 256;
            int r = idx >> 3, ku = idx & 7;
            uint4 va = make_uint4(0u, 0u, 0u, 0u);
            if (row0 + r < N)
                va = *(const uint4*)&A[(size_t)(row0 + r) * 128 + k0g + ku * 8];
            *(uint4*)&As[r * 72 + ku * 8] = va;
            uint4 vw = *(const uint4*)&Wt[(size_t)r * 128 + k0g + ku * 8];
            *(uint4*)&Ws[r * 72 + ku * 8] = vw;
        }
        __syncthreads();
#pragma unroll
        for (int kc = 0; kc < 2; kc++) {
            const int kl = kc * 32 + quad * 8;
            bf16x8 af[4], bfr[4];
#pragma unroll
            for (int t = 0; t < 4; t++) {
                af[t]  = *(const bf16x8*)&As[(wm * 64 + t * 16 + l16) * 72 + kl];
                bfr[t] = *(const bf16x8*)&Ws[(wn * 64 + t * 16 + l16) * 72 + kl];
            }
#pragma unroll
            for (int tm = 0; tm < 4; tm++)
#pragma unroll
                for (int tn = 0; tn < 4; tn++)
                    acc[tm][tn] = __builtin_amdgcn_mfma_f32_16x16x32_bf16(
                        af[tm], bfr[tn], acc[tm][tn], 0, 0, 0);
        }
    }

#pragma unroll
    for (int tm = 0; tm < 4; tm++) {
        const int rbase = row0 + wm * 64 + tm * 16 + quad * 4;
#pragma unroll
        for (int tn = 0; tn < 4; tn++) {
            const int col = wn * 64 + tn * 16 + l16;
#pragma unroll
            for (int r = 0; r < 4; r++) {
                if (rbase + r < N)
                    C[(size_t)(rbase + r) * 128 + col] = f2bf(acc[tm][tn][r]);
            }
        }
    }
}

// ---- fc: out[N,26](f32) = h[N,128](bf16) @ Wfc[128,26](f32) + bfc ----
__global__ __launch_bounds__(256) void gemmfc_k(const unsigned short* __restrict__ A,
                                                const float* __restrict__ W,
                                                const float* __restrict__ bias,
                                                float* __restrict__ C, int N) {
    constexpr int AP = 132;
    __shared__ float As[32 * AP];
    __shared__ float Ws[32 * 32];
    __shared__ float bs[32];
    const int tid  = threadIdx.x;
    const int wave = tid >> 6, lane = tid & 63;
    const int cg = lane & 7;
    const int rg = ((lane >> 3) & 7) | (wave << 3);
    const int row0 = blockIdx.x * 128;
    const int nrows = min(128, N - row0);

    if (tid < 32) bs[tid] = (tid < NCLASS) ? bias[tid] : 0.f;

    float acc[4][4];
#pragma unroll
    for (int i = 0; i < 4; i++)
#pragma unroll
        for (int jj = 0; jj < 4; jj++) acc[i][jj] = 0.f;

    for (int k0 = 0; k0 < 128; k0 += 32) {
        __syncthreads();
        for (int i = tid; i < 128 * 32; i += 256) {
            int r = i >> 5, k = i & 31;
            As[k * AP + r] = (r < nrows) ? bf2f(A[(size_t)(row0 + r) * 128 + k0 + k]) : 0.f;
        }
        for (int i = tid; i < 32 * 32; i += 256) {
            int k = i >> 5, c = i & 31;
            Ws[i] = (c < NCLASS) ? W[(size_t)(k0 + k) * NCLASS + c] : 0.f;
        }
        __syncthreads();
#pragma unroll 4
        for (int k = 0; k < 32; k++) {
            float4 a0 = *(const float4*)&As[k * AP + rg * 4];
            float4 w0 = *(const float4*)&Ws[k * 32 + cg * 4];
            float a[4] = {a0.x, a0.y, a0.z, a0.w};
            float w[4] = {w0.x, w0.y, w0.z, w0.w};
#pragma unroll
            for (int i = 0; i < 4; i++)
#pragma unroll
                for (int jj = 0; jj < 4; jj++)
                    acc[i][jj] = fmaf(a[i], w[jj], acc[i][jj]);
        }
    }

    const int c0 = cg * 4;
#pragma unroll
    for (int i = 0; i < 4; i++) {
        int r = rg * 4 + i;
        if (r < nrows && c0 < NCLASS) {
            float* dst = &C[(size_t)(row0 + r) * NCLASS + c0];
            if (c0 + 3 < NCLASS) {
                float4 v = {acc[i][0] + bs[c0], acc[i][1] + bs[c0 + 1],
                            acc[i][2] + bs[c0 + 2], acc[i][3] + bs[c0 + 3]};
                *(float4*)dst = v;
            } else {
                dst[0] = acc[i][0] + bs[c0];
                dst[1] = acc[i][1] + bs[c0 + 1];
            }
        }
    }
}

extern "C" void kernel_launch(void* const* d_in, const int* in_sizes, int n_in,
                              void* d_out, int out_size, void* d_ws, size_t ws_size,
                              hipStream_t stream) {
    const float* x   = (const float*)d_in[0];
    const int*   ei  = (const int*)d_in[1];
    const float* ew  = (const float*)d_in[2];
    const float* W1  = (const float*)d_in[3];
    const float* b1  = (const float*)d_in[4];
    const float* W2  = (const float*)d_in[5];
    const float* b2  = (const float*)d_in[6];
    const float* Wfc = (const float*)d_in[7];
    const float* bfc = (const float*)d_in[8];
    float* out = (float*)d_out;

    const int N = NNODES;
    const int* erow = ei;
    const int* ecol = ei + NEDGES;

    // ws layout (float-unit offsets):
    float* fws    = (float*)d_ws;
    float* dis    = fws;                                      // 100000
    int*   rowptr = (int*)(fws + 100000);                     // 100001 (+pad)
    int*   H      = (int*)(fws + 200004);                     // 114856
    int*   Hx     = (int*)(fws + 314860);                     // 114856
    int*   aux    = (int*)(fws + 429716);                     // 512
    uint2* rw     = (uint2*)(fws + 430228);                   // 600000 uint2
    unsigned short* lc = (unsigned short*)(fws + 1630228);    // 600000 u16
    uint2* meta   = (uint2*)(fws + 1930228);                  // 600000 uint2
    unsigned short* wt16  = (unsigned short*)(fws + 3130228); // 128*128 bf16
    unsigned short* w1t16 = (unsigned short*)(fws + 3138420); // 128*32 bf16
    unsigned int*   xp    = (unsigned int*)(fws + 3140468);   // N*16 uint
    unsigned int*   aggx  = (unsigned int*)(fws + 4740468);   // N*16 uint
    unsigned short* hA16  = (unsigned short*)(fws + 6340468); // N*128 bf16
    unsigned short* hB16  = (unsigned short*)(fws + 12740468);

    const int gScan = (NH + 255) / 256;   // 449
    const int g128  = (N + 127) / 128;    // 782
    const int gAgg  = N / 8;              // 12500
    const int gA26  = N / 16;             // 6250
    const int gPx   = (N * 16 + 255) / 256;
    const int gG1   = (N + 63) / 64;      // 1563

    // ---- CSR build ----
    histA_k<<<NBE, 256, 0, stream>>>(ecol, H);
    scanH1_k<<<gScan, 256, 0, stream>>>(H, Hx, aux, NH);
    scan2_k<<<1, 512, 0, stream>>>(aux, gScan);
    scanx_k<<<gScan, 256, 0, stream>>>(H, Hx, aux, NH);
    partB_k<<<NBE, 256, 0, stream>>>(erow, ecol, ew, Hx, rw, lc);
    segbuild_k<<<NBKT, 256, 0, stream>>>(rw, lc, Hx, rowptr, dis);
    segplace_k<<<NBKT, 256, 0, stream>>>(rw, lc, Hx, rowptr, dis, meta);
    wconv_k<<<64, 256, 0, stream>>>(W2, wt16);
    w1conv_k<<<16, 256, 0, stream>>>(W1, w1t16);
    padx_k<<<gPx, 256, 0, stream>>>(x, xp);

    // ---- layer 1 (reordered): agg26(x) -> gemm1(+b1, relu) ----
    agg26_k<<<gA26, 256, 0, stream>>>(rowptr, meta, xp, dis, aggx);
    gemm1_k<<<gG1, 256, 0, stream>>>((const unsigned short*)aggx, w1t16, b1, hA16, N);

    // ---- layer 2: gemm2 -> agg128(+b2, relu) ----
    gemm2_k<<<g128, 256, 0, stream>>>(hA16, wt16, hB16, N);
    agg_k<<<gAgg, 256, 0, stream>>>(rowptr, meta, (const uint2*)hB16, dis, b2,
                                    (uint2*)hA16);

    // ---- fc ----
    gemmfc_k<<<g128, 256, 0, stream>>>(hA16, Wfc, bfc, out, N);
}

// Round 10
// 235.396 us; speedup vs baseline: 4.3389x; 1.0499x over previous
//
#include <hip/hip_runtime.h>

#define NNODES 100000
#define NEDGES 600000
#define NCLASS 26
#define HID    128

#define SHIFT  9
#define BCOLS  512                    // cols per bucket
#define NBKT   196                    // ceil(100000/512)
#define EPB    1024                   // edges per partition block
#define NBE    586                    // ceil(600000/1024)
#define NH     (NBKT * NBE)           // 114856 histogram cells

typedef __attribute__((ext_vector_type(8))) short bf16x8;
typedef __attribute__((ext_vector_type(4))) float f32x4;

__device__ inline unsigned short f2bf(float f) {  // RNE fp32->bf16
    unsigned int u = __float_as_uint(f);
    u += 0x7fffu + ((u >> 16) & 1u);
    return (unsigned short)(u >> 16);
}
__device__ inline unsigned int packbf(float a, float b) {
    return (unsigned int)f2bf(a) | ((unsigned int)f2bf(b) << 16);
}
__device__ inline float2 bfpair(unsigned int p) {
    float2 r;
    r.x = __uint_as_float(p << 16);
    r.y = __uint_as_float(p & 0xffff0000u);
    return r;
}

// ---- pass A: per-block LDS histogram of edge->bucket ----
__global__ __launch_bounds__(256) void histA_k(const int* __restrict__ col,
                                               int* __restrict__ H) {
    __shared__ int h[NBKT];
    int t = threadIdx.x;
    for (int i = t; i < NBKT; i += 256) h[i] = 0;
    __syncthreads();
    int base = blockIdx.x * EPB;
#pragma unroll
    for (int u = 0; u < 4; u++) {
        int e = base + t + u * 256;
        if (e < NEDGES) atomicAdd(&h[col[e] >> SHIFT], 1);
    }
    __syncthreads();
    for (int i = t; i < NBKT; i += 256) H[i * NBE + blockIdx.x] = h[i];
}

__global__ void scanH1_k(const int* __restrict__ in, int* __restrict__ incl,
                         int* __restrict__ aux, int n) {
    __shared__ int s[256];
    int t = threadIdx.x, gi = blockIdx.x * 256 + t;
    s[t] = (gi < n) ? in[gi] : 0;
    __syncthreads();
    for (int off = 1; off < 256; off <<= 1) {
        int x = (t >= off) ? s[t - off] : 0;
        __syncthreads();
        s[t] += x;
        __syncthreads();
    }
    if (gi < n) incl[gi] = s[t];
    if (t == 255) aux[blockIdx.x] = s[255];
}

__global__ void scan2_k(int* __restrict__ aux, int n) {  // 1 block, 512 thr
    __shared__ int s[512];
    int t = threadIdx.x;
    s[t] = (t < n) ? aux[t] : 0;
    __syncthreads();
    for (int off = 1; off < 512; off <<= 1) {
        int x = (t >= off) ? s[t - off] : 0;
        __syncthreads();
        s[t] += x;
        __syncthreads();
    }
    if (t < n) aux[t] = s[t];
}

// exclusive offset of cell gi, reconstructed from incl/H/aux
__device__ inline int exoff(const int* __restrict__ incl, const int* __restrict__ H,
                            const int* __restrict__ aux, int gi) {
    int add = (gi >= 256) ? aux[(gi >> 8) - 1] : 0;
    return incl[gi] - H[gi] + add;
}

// ---- pass B: partition edges into bucket-contiguous storage ----
__global__ __launch_bounds__(256) void partB_k(const int* __restrict__ row,
                                               const int* __restrict__ col,
                                               const float* __restrict__ w,
                                               const int* __restrict__ incl,
                                               const int* __restrict__ H,
                                               const int* __restrict__ aux,
                                               uint2* __restrict__ rw,
                                               unsigned short* __restrict__ lc) {
    __shared__ int off[NBKT];
    __shared__ int cur[NBKT];
    int t = threadIdx.x;
    for (int i = t; i < NBKT; i += 256) {
        off[i] = exoff(incl, H, aux, i * NBE + blockIdx.x);
        cur[i] = 0;
    }
    __syncthreads();
    int base = blockIdx.x * EPB;
#pragma unroll
    for (int u = 0; u < 4; u++) {
        int e = base + t + u * 256;
        if (e < NEDGES) {
            int c = col[e], b = c >> SHIFT;
            int p = off[b] + atomicAdd(&cur[b], 1);
            rw[p] = make_uint2((unsigned int)row[e], __float_as_uint(w[e]));
            lc[p] = (unsigned short)(c & (BCOLS - 1));
        }
    }
}

// ---- fused per-bucket: degree/wsum -> dis + rowptr (LDS scan) -> place meta ----
// meta = (src, w) only: dis[src] is baked into hs at the producer side.
__global__ __launch_bounds__(256) void segbp_k(const uint2* __restrict__ rw,
                                               const unsigned short* __restrict__ lc,
                                               const int* __restrict__ incl,
                                               const int* __restrict__ H,
                                               const int* __restrict__ aux,
                                               int* __restrict__ rowptr,
                                               float* __restrict__ dis,
                                               uint2* __restrict__ meta) {
    __shared__ int   cnt[BCOLS];
    __shared__ float ws[BCOLS];
    __shared__ int   rpl[BCOLS];
    __shared__ int   ps[256];
    int b = blockIdx.x, t = threadIdx.x;
    int c0 = b << SHIFT;
    int ncols = min(BCOLS, NNODES - c0);
    for (int i = t; i < BCOLS; i += 256) { cnt[i] = 0; ws[i] = 0.f; }
    __syncthreads();
    int s    = exoff(incl, H, aux, b * NBE);
    int eend = (b == NBKT - 1) ? NEDGES : exoff(incl, H, aux, (b + 1) * NBE);
    // pass 1: count + weight-sum
    for (int e = s + t; e < eend; e += 256) {
        uint2 m = rw[e];
        int l = lc[e];
        atomicAdd(&cnt[l], 1);
        atomicAdd(&ws[l], __uint_as_float(m.y));
    }
    __syncthreads();
    for (int i = t; i < ncols; i += 256) dis[c0 + i] = rsqrtf(1.0f + ws[i]);
    // exclusive scan of cnt (2 elems/thread, Hillis-Steele on partials)
    int a0 = cnt[2 * t], a1 = cnt[2 * t + 1];
    ps[t] = a0 + a1;
    __syncthreads();
    for (int off = 1; off < 256; off <<= 1) {
        int x = (t >= off) ? ps[t - off] : 0;
        __syncthreads();
        ps[t] += x;
        __syncthreads();
    }
    int ex = (t > 0) ? ps[t - 1] : 0;
    rpl[2 * t]     = s + ex;
    rpl[2 * t + 1] = s + ex + a0;
    if (2 * t     < ncols) rowptr[c0 + 2 * t]     = s + ex;
    if (2 * t + 1 < ncols) rowptr[c0 + 2 * t + 1] = s + ex + a0;
    if (b == NBKT - 1 && t == 0) rowptr[NNODES] = NEDGES;
    cnt[2 * t] = 0; cnt[2 * t + 1] = 0;   // reuse as cursors
    __syncthreads();
    // pass 2: place (rw/lc re-read is L2-hot, ~30 KB/bucket)
    for (int e = s + t; e < eend; e += 256) {
        uint2 m = rw[e];
        int l = lc[e];
        int pos = rpl[l] + atomicAdd(&cnt[l], 1);
        meta[pos] = make_uint2(m.x, m.y);   // (src, w)
    }
}

// ---- fused prep: W2^T bf16 | W1^T padded bf16 | Wfc^T padded bf16 | xs = dis*x ----
__global__ __launch_bounds__(256) void prep_k(const float* __restrict__ W2,
                                              const float* __restrict__ W1,
                                              const float* __restrict__ Wfc,
                                              const float* __restrict__ x,
                                              const float* __restrict__ dis,
                                              unsigned short* __restrict__ wt,
                                              unsigned short* __restrict__ w1t,
                                              unsigned short* __restrict__ wfct,
                                              unsigned int* __restrict__ xp) {
    int b = blockIdx.x, t = threadIdx.x;
    if (b < 64) {                       // W2 -> wt[c*128+k]
        int idx = b * 256 + t;
        int c = idx >> 7, k = idx & 127;
        wt[c * 128 + k] = f2bf(W2[k * 128 + c]);
    } else if (b < 80) {                // W1 -> w1t[c*32+k], k>=26 zero
        int idx = (b - 64) * 256 + t;
        int c = idx >> 5, k = idx & 31;
        w1t[c * 32 + k] = (k < NCLASS) ? f2bf(W1[k * 128 + c]) : (unsigned short)0;
    } else if (b < 96) {                // Wfc -> wfct[c*128+k], c>=26 zero
        int idx = (b - 80) * 256 + t;
        int c = idx >> 7, k = idx & 127;
        wfct[c * 128 + k] = (c < NCLASS) ? f2bf(Wfc[k * NCLASS + c]) : (unsigned short)0;
    } else {                            // xs[r] = dis[r] * x[r], padded to 32, bf16
        int i = (b - 96) * 256 + t;
        if (i < NNODES * 16) {
            int r = i >> 4, u = i & 15, f0 = u * 2;
            float d = dis[r];
            float a = (f0     < NCLASS) ? x[r * NCLASS + f0]     : 0.f;
            float c = (f0 + 1 < NCLASS) ? x[r * NCLASS + f0 + 1] : 0.f;
            xp[i] = packbf(d * a, d * c);
        }
    }
}

// ---- agg 26-dim: acc = xs[dst] + sum w*xs[src]; aggx = d_dst * acc ----
__global__ __launch_bounds__(256) void agg26_k(const int* __restrict__ rowptr,
                                               const uint2* __restrict__ meta,
                                               const unsigned int* __restrict__ xp,
                                               const float* __restrict__ dis,
                                               unsigned int* __restrict__ aggx) {
    int node = blockIdx.x * 16 + (threadIdx.x >> 4);
    int lane = threadIdx.x & 15;

    float2 acc = bfpair(xp[node * 16 + lane]);
    int j = rowptr[node], jend = rowptr[node + 1];
    for (; j + 3 < jend; j += 4) {
        uint2 m0 = meta[j],     m1 = meta[j + 1];
        uint2 m2 = meta[j + 2], m3 = meta[j + 3];
        unsigned int g0 = xp[m0.x * 16 + lane];
        unsigned int g1 = xp[m1.x * 16 + lane];
        unsigned int g2 = xp[m2.x * 16 + lane];
        unsigned int g3 = xp[m3.x * 16 + lane];
        float v0 = __uint_as_float(m0.y), v1 = __uint_as_float(m1.y);
        float v2 = __uint_as_float(m2.y), v3 = __uint_as_float(m3.y);
        float2 a;
        a = bfpair(g0); acc.x = fmaf(v0, a.x, acc.x); acc.y = fmaf(v0, a.y, acc.y);
        a = bfpair(g1); acc.x = fmaf(v1, a.x, acc.x); acc.y = fmaf(v1, a.y, acc.y);
        a = bfpair(g2); acc.x = fmaf(v2, a.x, acc.x); acc.y = fmaf(v2, a.y, acc.y);
        a = bfpair(g3); acc.x = fmaf(v3, a.x, acc.x); acc.y = fmaf(v3, a.y, acc.y);
    }
    for (; j < jend; j++) {
        uint2 m = meta[j];
        float v = __uint_as_float(m.y);
        float2 a = bfpair(xp[m.x * 16 + lane]);
        acc.x = fmaf(v, a.x, acc.x); acc.y = fmaf(v, a.y, acc.y);
    }
    float d = dis[node];
    aggx[node * 16 + lane] = packbf(d * acc.x, d * acc.y);
}

// ---- gemm1 (MFMA, K=32): h1 = relu(aggx @ W1 + b1), bf16 out ----
__global__ __launch_bounds__(256) void gemm1_k(const unsigned short* __restrict__ aggx,
                                               const unsigned short* __restrict__ w1t,
                                               const float* __restrict__ bias,
                                               unsigned short* __restrict__ C, int N) {
    const int tid  = threadIdx.x;
    const int wv = tid >> 6, lane = tid & 63;
    const int quad = lane >> 4, l16 = lane & 15;
    const int row0 = blockIdx.x * 64 + wv * 16;

    bf16x8 bf[8];
#pragma unroll
    for (int n = 0; n < 8; n++)
        bf[n] = *(const bf16x8*)&w1t[(n * 16 + l16) * 32 + quad * 8];

    bf16x8 af = (bf16x8)(short)0;
    int arow = row0 + l16;
    if (arow < N) af = *(const bf16x8*)&aggx[(size_t)arow * 32 + quad * 8];

#pragma unroll
    for (int n = 0; n < 8; n++) {
        f32x4 acc = __builtin_amdgcn_mfma_f32_16x16x32_bf16(af, bf[n], (f32x4)0.f, 0, 0, 0);
        int col = n * 16 + l16;
        float bv = bias[col];
        int r0 = row0 + quad * 4;
#pragma unroll
        for (int r = 0; r < 4; r++) {
            if (r0 + r < N)
                C[(size_t)(r0 + r) * 128 + col] = f2bf(fmaxf(acc[r] + bv, 0.f));
        }
    }
}

// ---- GEMM2 (MFMA bf16): t2s[N,128] = dis * (A @ W2), bf16 out ----
__global__ __launch_bounds__(256) void gemm2_k(const unsigned short* __restrict__ A,
                                               const unsigned short* __restrict__ Wt,
                                               const float* __restrict__ dis,
                                               unsigned short* __restrict__ C, int N) {
    __shared__ unsigned short As[128 * 72];
    __shared__ unsigned short Ws[128 * 72];
    const int tid  = threadIdx.x;
    const int wave = tid >> 6, lane = tid & 63;
    const int quad = lane >> 4, l16 = lane & 15;
    const int wm = wave >> 1, wn = wave & 1;
    const int row0 = blockIdx.x * 128;

    f32x4 acc[4][4];
#pragma unroll
    for (int i = 0; i < 4; i++)
#pragma unroll
        for (int j = 0; j < 4; j++) acc[i][j] = (f32x4)0.f;

    for (int c = 0; c < 2; c++) {
        const int k0g = c * 64;
        __syncthreads();
#pragma unroll
        for (int j = 0; j < 4; j++) {
            int idx = tid + j * 256;
            int r = idx >> 3, ku = idx & 7;
            uint4 va = make_uint4(0u, 0u, 0u, 0u);
            if (row0 + r < N)
                va = *(const uint4*)&A[(size_t)(row0 + r) * 128 + k0g + ku * 8];
            *(uint4*)&As[r * 72 + ku * 8] = va;
            uint4 vw = *(const uint4*)&Wt[(size_t)r * 128 + k0g + ku * 8];
            *(uint4*)&Ws[r * 72 + ku * 8] = vw;
        }
        __syncthreads();
#pragma unroll
        for (int kc = 0; kc < 2; kc++) {
            const int kl = kc * 32 + quad * 8;
            bf16x8 af[4], bfr[4];
#pragma unroll
            for (int t = 0; t < 4; t++) {
                af[t]  = *(const bf16x8*)&As[(wm * 64 + t * 16 + l16) * 72 + kl];
                bfr[t] = *(const bf16x8*)&Ws[(wn * 64 + t * 16 + l16) * 72 + kl];
            }
#pragma unroll
            for (int tm = 0; tm < 4; tm++)
#pragma unroll
                for (int tn = 0; tn < 4; tn++)
                    acc[tm][tn] = __builtin_amdgcn_mfma_f32_16x16x32_bf16(
                        af[tm], bfr[tn], acc[tm][tn], 0, 0, 0);
        }
    }

#pragma unroll
    for (int tm = 0; tm < 4; tm++) {
        const int rbase = row0 + wm * 64 + tm * 16 + quad * 4;
        float dv[4];
#pragma unroll
        for (int r = 0; r < 4; r++)
            dv[r] = (rbase + r < N) ? dis[rbase + r] : 0.f;
#pragma unroll
        for (int tn = 0; tn < 4; tn++) {
            const int col = wn * 64 + tn * 16 + l16;
#pragma unroll
            for (int r = 0; r < 4; r++) {
                if (rbase + r < N)
                    C[(size_t)(rbase + r) * 128 + col] = f2bf(dv[r] * acc[tm][tn][r]);
            }
        }
    }
}

// ---- agg 128-dim: acc = t2s[dst] + sum w*t2s[src]; h2 = relu(d*acc + b2) ----
__global__ __launch_bounds__(256) void agg_k(const int* __restrict__ rowptr,
                                             const uint2* __restrict__ meta,
                                             const uint2* __restrict__ h,
                                             const float* __restrict__ dis,
                                             const float* __restrict__ bias,
                                             uint2* __restrict__ out) {
    int node = blockIdx.x * 8 + (threadIdx.x >> 5);
    if (node >= NNODES) return;
    int lane = threadIdx.x & 31;

    uint2 hcu = h[node * 32 + lane];
    float2 h0 = bfpair(hcu.x), h1 = bfpair(hcu.y);
    float4 acc;
    acc.x = h0.x; acc.y = h0.y; acc.z = h1.x; acc.w = h1.y;

    int j = rowptr[node], jend = rowptr[node + 1];
    for (; j + 3 < jend; j += 4) {
        uint2 m0 = meta[j],     m1 = meta[j + 1];
        uint2 m2 = meta[j + 2], m3 = meta[j + 3];
        uint2 g0 = h[m0.x * 32 + lane];
        uint2 g1 = h[m1.x * 32 + lane];
        uint2 g2 = h[m2.x * 32 + lane];
        uint2 g3 = h[m3.x * 32 + lane];
        float v0 = __uint_as_float(m0.y), v1 = __uint_as_float(m1.y);
        float v2 = __uint_as_float(m2.y), v3 = __uint_as_float(m3.y);
        float2 a, b;
        a = bfpair(g0.x); b = bfpair(g0.y);
        acc.x = fmaf(v0, a.x, acc.x); acc.y = fmaf(v0, a.y, acc.y);
        acc.z = fmaf(v0, b.x, acc.z); acc.w = fmaf(v0, b.y, acc.w);
        a = bfpair(g1.x); b = bfpair(g1.y);
        acc.x = fmaf(v1, a.x, acc.x); acc.y = fmaf(v1, a.y, acc.y);
        acc.z = fmaf(v1, b.x, acc.z); acc.w = fmaf(v1, b.y, acc.w);
        a = bfpair(g2.x); b = bfpair(g2.y);
        acc.x = fmaf(v2, a.x, acc.x); acc.y = fmaf(v2, a.y, acc.y);
        acc.z = fmaf(v2, b.x, acc.z); acc.w = fmaf(v2, b.y, acc.w);
        a = bfpair(g3.x); b = bfpair(g3.y);
        acc.x = fmaf(v3, a.x, acc.x); acc.y = fmaf(v3, a.y, acc.y);
        acc.z = fmaf(v3, b.x, acc.z); acc.w = fmaf(v3, b.y, acc.w);
    }
    for (; j < jend; j++) {
        uint2 m = meta[j];
        float v = __uint_as_float(m.y);
        uint2 g = h[m.x * 32 + lane];
        float2 a = bfpair(g.x), b = bfpair(g.y);
        acc.x = fmaf(v, a.x, acc.x); acc.y = fmaf(v, a.y, acc.y);
        acc.z = fmaf(v, b.x, acc.z); acc.w = fmaf(v, b.y, acc.w);
    }

    float d = dis[node];
    float4 bv = ((const float4*)bias)[lane];
    acc.x = fmaxf(fmaf(d, acc.x, bv.x), 0.f);
    acc.y = fmaxf(fmaf(d, acc.y, bv.y), 0.f);
    acc.z = fmaxf(fmaf(d, acc.z, bv.z), 0.f);
    acc.w = fmaxf(fmaf(d, acc.w, bv.w), 0.f);
    out[node * 32 + lane] = make_uint2(packbf(acc.x, acc.y), packbf(acc.z, acc.w));
}

// ---- fc (MFMA, K=128): out[N,26] f32 = h2 @ Wfc + bfc ----
__global__ __launch_bounds__(256) void gemmfc_k(const unsigned short* __restrict__ A,
                                                const unsigned short* __restrict__ wfct,
                                                const float* __restrict__ bias,
                                                float* __restrict__ C, int N) {
    const int tid  = threadIdx.x;
    const int wv = tid >> 6, lane = tid & 63;
    const int quad = lane >> 4, l16 = lane & 15;
    const int row0 = blockIdx.x * 64 + wv * 16;

    bf16x8 af[4];
    int arow = row0 + l16;
    bool av = arow < N;
#pragma unroll
    for (int ks = 0; ks < 4; ks++)
        af[ks] = av ? *(const bf16x8*)&A[(size_t)arow * 128 + ks * 32 + quad * 8]
                    : (bf16x8)(short)0;

#pragma unroll
    for (int n = 0; n < 2; n++) {
        f32x4 acc = (f32x4)0.f;
#pragma unroll
        for (int ks = 0; ks < 4; ks++) {
            bf16x8 bf = *(const bf16x8*)&wfct[(size_t)(n * 16 + l16) * 128 + ks * 32 + quad * 8];
            acc = __builtin_amdgcn_mfma_f32_16x16x32_bf16(af[ks], bf, acc, 0, 0, 0);
        }
        int col = n * 16 + l16;
        if (col < NCLASS) {
            float bv = bias[col];
            int r0 = row0 + quad * 4;
#pragma unroll
            for (int r = 0; r < 4; r++) {
                if (r0 + r < N)
                    C[(size_t)(r0 + r) * NCLASS + col] = acc[r] + bv;
            }
        }
    }
}

extern "C" void kernel_launch(void* const* d_in, const int* in_sizes, int n_in,
                              void* d_out, int out_size, void* d_ws, size_t ws_size,
                              hipStream_t stream) {
    const float* x   = (const float*)d_in[0];
    const int*   ei  = (const int*)d_in[1];
    const float* ew  = (const float*)d_in[2];
    const float* W1  = (const float*)d_in[3];
    const float* b1  = (const float*)d_in[4];
    const float* W2  = (const float*)d_in[5];
    const float* b2  = (const float*)d_in[6];
    const float* Wfc = (const float*)d_in[7];
    const float* bfc = (const float*)d_in[8];
    float* out = (float*)d_out;

    const int N = NNODES;
    const int* erow = ei;
    const int* ecol = ei + NEDGES;

    // ws layout (float-unit offsets):
    float* fws    = (float*)d_ws;
    float* dis    = fws;                                       // 100000
    int*   rowptr = (int*)(fws + 100000);                      // 100001 (+pad)
    int*   H      = (int*)(fws + 200004);                      // 114856
    int*   incl   = (int*)(fws + 314860);                      // 114856
    int*   aux    = (int*)(fws + 429716);                      // 512
    uint2* rw     = (uint2*)(fws + 430228);                    // 600000 uint2
    unsigned short* lc = (unsigned short*)(fws + 1630228);     // 600000 u16
    uint2* meta   = (uint2*)(fws + 1930228);                   // 600000 uint2
    unsigned short* wt16   = (unsigned short*)(fws + 3130228); // 128*128
    unsigned short* w1t16  = (unsigned short*)(fws + 3138420); // 128*32
    unsigned short* wfct16 = (unsigned short*)(fws + 3140468); // 32*128
    unsigned int*   xp     = (unsigned int*)(fws + 3142516);   // N*16
    unsigned int*   aggx   = (unsigned int*)(fws + 4742516);   // N*16
    unsigned short* hA16   = (unsigned short*)(fws + 6342516); // N*128
    unsigned short* hB16   = (unsigned short*)(fws + 12742516);

    const int gScan = (NH + 255) / 256;   // 449
    const int g128  = (N + 127) / 128;    // 782
    const int gAgg  = N / 8;              // 12500
    const int gA26  = N / 16;             // 6250
    const int gPrep = 96 + (N * 16 + 255) / 256;  // 96 + 6250
    const int gG1   = (N + 63) / 64;      // 1563

    // ---- CSR build (5 kernels) ----
    histA_k<<<NBE, 256, 0, stream>>>(ecol, H);
    scanH1_k<<<gScan, 256, 0, stream>>>(H, incl, aux, NH);
    scan2_k<<<1, 512, 0, stream>>>(aux, gScan);
    partB_k<<<NBE, 256, 0, stream>>>(erow, ecol, ew, incl, H, aux, rw, lc);
    segbp_k<<<NBKT, 256, 0, stream>>>(rw, lc, incl, H, aux, rowptr, dis, meta);

    // ---- prep (needs dis for xs) ----
    prep_k<<<gPrep, 256, 0, stream>>>(W2, W1, Wfc, x, dis, wt16, w1t16, wfct16, xp);

    // ---- layer 1: agg26(xs) -> gemm1(+b1, relu) ----
    agg26_k<<<gA26, 256, 0, stream>>>(rowptr, meta, xp, dis, aggx);
    gemm1_k<<<gG1, 256, 0, stream>>>((const unsigned short*)aggx, w1t16, b1, hA16, N);

    // ---- layer 2: gemm2 (dis epilogue) -> agg128(+b2, relu) ----
    gemm2_k<<<g128, 256, 0, stream>>>(hA16, wt16, dis, hB16, N);
    agg_k<<<gAgg, 256, 0, stream>>>(rowptr, meta, (const uint2*)hB16, dis, b2,
                                    (uint2*)hA16);

    // ---- fc (MFMA) ----
    gemmfc_k<<<gG1, 256, 0, stream>>>(hA16, wfct16, bfc, out, N);
}

// Round 11
// 213.770 us; speedup vs baseline: 4.7778x; 1.1012x over previous
//
#include <hip/hip_runtime.h>

#define NNODES 100000
#define NEDGES 600000
#define NCLASS 26
#define HID    128

#define SHIFT  9
#define BCOLS  512                    // cols per bucket
#define NBKT   196                    // ceil(100000/512)
#define EPB    1024                   // edges per partition block
#define NBE    586                    // ceil(600000/1024)
#define NH     (NBKT * NBE)           // 114856 histogram cells

typedef __attribute__((ext_vector_type(8))) short bf16x8;
typedef __attribute__((ext_vector_type(4))) float f32x4;

__device__ inline unsigned short f2bf(float f) {  // RNE fp32->bf16
    unsigned int u = __float_as_uint(f);
    u += 0x7fffu + ((u >> 16) & 1u);
    return (unsigned short)(u >> 16);
}
__device__ inline unsigned int packbf(float a, float b) {
    return (unsigned int)f2bf(a) | ((unsigned int)f2bf(b) << 16);
}
__device__ inline float2 bfpair(unsigned int p) {
    float2 r;
    r.x = __uint_as_float(p << 16);
    r.y = __uint_as_float(p & 0xffff0000u);
    return r;
}
__device__ inline void fma8(float* a, float w, uint4 g) {
    float2 p;
    p = bfpair(g.x); a[0] = fmaf(w, p.x, a[0]); a[1] = fmaf(w, p.y, a[1]);
    p = bfpair(g.y); a[2] = fmaf(w, p.x, a[2]); a[3] = fmaf(w, p.y, a[3]);
    p = bfpair(g.z); a[4] = fmaf(w, p.x, a[4]); a[5] = fmaf(w, p.y, a[5]);
    p = bfpair(g.w); a[6] = fmaf(w, p.x, a[6]); a[7] = fmaf(w, p.y, a[7]);
}
__device__ inline void set8(float* a, uint4 g) {
    float2 p;
    p = bfpair(g.x); a[0] = p.x; a[1] = p.y;
    p = bfpair(g.y); a[2] = p.x; a[3] = p.y;
    p = bfpair(g.z); a[4] = p.x; a[5] = p.y;
    p = bfpair(g.w); a[6] = p.x; a[7] = p.y;
}

// ---- pass A: per-block LDS histogram of edge->bucket ----
__global__ __launch_bounds__(256) void histA_k(const int* __restrict__ col,
                                               int* __restrict__ H) {
    __shared__ int h[NBKT];
    int t = threadIdx.x;
    for (int i = t; i < NBKT; i += 256) h[i] = 0;
    __syncthreads();
    int base = blockIdx.x * EPB;
#pragma unroll
    for (int u = 0; u < 4; u++) {
        int e = base + t + u * 256;
        if (e < NEDGES) atomicAdd(&h[col[e] >> SHIFT], 1);
    }
    __syncthreads();
    for (int i = t; i < NBKT; i += 256) H[i * NBE + blockIdx.x] = h[i];
}

__global__ void scanH1_k(const int* __restrict__ in, int* __restrict__ incl,
                         int* __restrict__ aux, int n) {
    __shared__ int s[256];
    int t = threadIdx.x, gi = blockIdx.x * 256 + t;
    s[t] = (gi < n) ? in[gi] : 0;
    __syncthreads();
    for (int off = 1; off < 256; off <<= 1) {
        int x = (t >= off) ? s[t - off] : 0;
        __syncthreads();
        s[t] += x;
        __syncthreads();
    }
    if (gi < n) incl[gi] = s[t];
    if (t == 255) aux[blockIdx.x] = s[255];
}

__global__ void scan2_k(int* __restrict__ aux, int n) {  // 1 block, 512 thr
    __shared__ int s[512];
    int t = threadIdx.x;
    s[t] = (t < n) ? aux[t] : 0;
    __syncthreads();
    for (int off = 1; off < 512; off <<= 1) {
        int x = (t >= off) ? s[t - off] : 0;
        __syncthreads();
        s[t] += x;
        __syncthreads();
    }
    if (t < n) aux[t] = s[t];
}

// exclusive offset of cell gi, reconstructed from incl/H/aux
__device__ inline int exoff(const int* __restrict__ incl, const int* __restrict__ H,
                            const int* __restrict__ aux, int gi) {
    int add = (gi >= 256) ? aux[(gi >> 8) - 1] : 0;
    return incl[gi] - H[gi] + add;
}

// ---- pass B: partition edges into bucket-contiguous storage ----
__global__ __launch_bounds__(256) void partB_k(const int* __restrict__ row,
                                               const int* __restrict__ col,
                                               const float* __restrict__ w,
                                               const int* __restrict__ incl,
                                               const int* __restrict__ H,
                                               const int* __restrict__ aux,
                                               uint2* __restrict__ rw,
                                               unsigned short* __restrict__ lc) {
    __shared__ int off[NBKT];
    __shared__ int cur[NBKT];
    int t = threadIdx.x;
    for (int i = t; i < NBKT; i += 256) {
        off[i] = exoff(incl, H, aux, i * NBE + blockIdx.x);
        cur[i] = 0;
    }
    __syncthreads();
    int base = blockIdx.x * EPB;
#pragma unroll
    for (int u = 0; u < 4; u++) {
        int e = base + t + u * 256;
        if (e < NEDGES) {
            int c = col[e], b = c >> SHIFT;
            int p = off[b] + atomicAdd(&cur[b], 1);
            rw[p] = make_uint2((unsigned int)row[e], __float_as_uint(w[e]));
            lc[p] = (unsigned short)(c & (BCOLS - 1));
        }
    }
}

// ---- fused per-bucket: degree/wsum -> dis + rowptr (LDS scan) -> place meta ----
__global__ __launch_bounds__(256) void segbp_k(const uint2* __restrict__ rw,
                                               const unsigned short* __restrict__ lc,
                                               const int* __restrict__ incl,
                                               const int* __restrict__ H,
                                               const int* __restrict__ aux,
                                               int* __restrict__ rowptr,
                                               float* __restrict__ dis,
                                               uint2* __restrict__ meta) {
    __shared__ int   cnt[BCOLS];
    __shared__ float ws[BCOLS];
    __shared__ int   rpl[BCOLS];
    __shared__ int   ps[256];
    int b = blockIdx.x, t = threadIdx.x;
    int c0 = b << SHIFT;
    int ncols = min(BCOLS, NNODES - c0);
    for (int i = t; i < BCOLS; i += 256) { cnt[i] = 0; ws[i] = 0.f; }
    __syncthreads();
    int s    = exoff(incl, H, aux, b * NBE);
    int eend = (b == NBKT - 1) ? NEDGES : exoff(incl, H, aux, (b + 1) * NBE);
    for (int e = s + t; e < eend; e += 256) {
        uint2 m = rw[e];
        int l = lc[e];
        atomicAdd(&cnt[l], 1);
        atomicAdd(&ws[l], __uint_as_float(m.y));
    }
    __syncthreads();
    for (int i = t; i < ncols; i += 256) dis[c0 + i] = rsqrtf(1.0f + ws[i]);
    int a0 = cnt[2 * t], a1 = cnt[2 * t + 1];
    ps[t] = a0 + a1;
    __syncthreads();
    for (int off = 1; off < 256; off <<= 1) {
        int x = (t >= off) ? ps[t - off] : 0;
        __syncthreads();
        ps[t] += x;
        __syncthreads();
    }
    int ex = (t > 0) ? ps[t - 1] : 0;
    rpl[2 * t]     = s + ex;
    rpl[2 * t + 1] = s + ex + a0;
    if (2 * t     < ncols) rowptr[c0 + 2 * t]     = s + ex;
    if (2 * t + 1 < ncols) rowptr[c0 + 2 * t + 1] = s + ex + a0;
    if (b == NBKT - 1 && t == 0) rowptr[NNODES] = NEDGES;
    cnt[2 * t] = 0; cnt[2 * t + 1] = 0;   // reuse as cursors
    __syncthreads();
    for (int e = s + t; e < eend; e += 256) {
        uint2 m = rw[e];
        int l = lc[e];
        int pos = rpl[l] + atomicAdd(&cnt[l], 1);
        meta[pos] = make_uint2(m.x, m.y);   // (src, w)
    }
}

// ---- fused prep: W2^T bf16 | W1^T padded bf16 | Wfc^T padded bf16 | xs = dis*x ----
__global__ __launch_bounds__(256) void prep_k(const float* __restrict__ W2,
                                              const float* __restrict__ W1,
                                              const float* __restrict__ Wfc,
                                              const float* __restrict__ x,
                                              const float* __restrict__ dis,
                                              unsigned short* __restrict__ wt,
                                              unsigned short* __restrict__ w1t,
                                              unsigned short* __restrict__ wfct,
                                              unsigned int* __restrict__ xp) {
    int b = blockIdx.x, t = threadIdx.x;
    if (b < 64) {
        int idx = b * 256 + t;
        int c = idx >> 7, k = idx & 127;
        wt[c * 128 + k] = f2bf(W2[k * 128 + c]);
    } else if (b < 80) {
        int idx = (b - 64) * 256 + t;
        int c = idx >> 5, k = idx & 31;
        w1t[c * 32 + k] = (k < NCLASS) ? f2bf(W1[k * 128 + c]) : (unsigned short)0;
    } else if (b < 96) {
        int idx = (b - 80) * 256 + t;
        int c = idx >> 7, k = idx & 127;
        wfct[c * 128 + k] = (c < NCLASS) ? f2bf(Wfc[k * NCLASS + c]) : (unsigned short)0;
    } else {
        int i = (b - 96) * 256 + t;
        if (i < NNODES * 16) {
            int r = i >> 4, u = i & 15, f0 = u * 2;
            float d = dis[r];
            float a = (f0     < NCLASS) ? x[r * NCLASS + f0]     : 0.f;
            float c = (f0 + 1 < NCLASS) ? x[r * NCLASS + f0 + 1] : 0.f;
            xp[i] = packbf(d * a, d * c);
        }
    }
}

// ---- agg 26-dim: acc = xs[dst] + sum w*xs[src]; aggx = d_dst * acc (bf16 [N,32]) ----
__global__ __launch_bounds__(256) void agg26_k(const int* __restrict__ rowptr,
                                               const uint2* __restrict__ meta,
                                               const unsigned int* __restrict__ xp,
                                               const float* __restrict__ dis,
                                               unsigned int* __restrict__ aggx) {
    int node = blockIdx.x * 16 + (threadIdx.x >> 4);
    int lane = threadIdx.x & 15;

    float2 acc = bfpair(xp[node * 16 + lane]);
    int j = rowptr[node], jend = rowptr[node + 1];
    for (; j + 3 < jend; j += 4) {
        uint2 m0 = meta[j],     m1 = meta[j + 1];
        uint2 m2 = meta[j + 2], m3 = meta[j + 3];
        unsigned int g0 = xp[m0.x * 16 + lane];
        unsigned int g1 = xp[m1.x * 16 + lane];
        unsigned int g2 = xp[m2.x * 16 + lane];
        unsigned int g3 = xp[m3.x * 16 + lane];
        float v0 = __uint_as_float(m0.y), v1 = __uint_as_float(m1.y);
        float v2 = __uint_as_float(m2.y), v3 = __uint_as_float(m3.y);
        float2 a;
        a = bfpair(g0); acc.x = fmaf(v0, a.x, acc.x); acc.y = fmaf(v0, a.y, acc.y);
        a = bfpair(g1); acc.x = fmaf(v1, a.x, acc.x); acc.y = fmaf(v1, a.y, acc.y);
        a = bfpair(g2); acc.x = fmaf(v2, a.x, acc.x); acc.y = fmaf(v2, a.y, acc.y);
        a = bfpair(g3); acc.x = fmaf(v3, a.x, acc.x); acc.y = fmaf(v3, a.y, acc.y);
    }
    for (; j < jend; j++) {
        uint2 m = meta[j];
        float v = __uint_as_float(m.y);
        float2 a = bfpair(xp[m.x * 16 + lane]);
        acc.x = fmaf(v, a.x, acc.x); acc.y = fmaf(v, a.y, acc.y);
    }
    float d = dis[node];
    aggx[node * 16 + lane] = packbf(d * acc.x, d * acc.y);
}

// ---- fused gemm1+gemm2: t2s = dis * (relu(aggx@W1 + b1) @ W2), bf16 out ----
// h1 tile (128x128) computed via one K=32 MFMA step per 16x16 tile (A/B frags
// straight from global), kept in LDS; then the W2 K-loop reads it.
__global__ __launch_bounds__(256) void gemm12_k(const unsigned short* __restrict__ aggx,
                                                const unsigned short* __restrict__ w1t,
                                                const float* __restrict__ b1,
                                                const unsigned short* __restrict__ wt,
                                                const float* __restrict__ dis,
                                                unsigned short* __restrict__ C, int N) {
    __shared__ unsigned short h1s[128 * 136];  // h1 tile, stride 136 (16B-aligned rows)
    __shared__ unsigned short Ws[128 * 72];    // W2^T k-chunk staging
    const int tid  = threadIdx.x;
    const int wave = tid >> 6, lane = tid & 63;
    const int quad = lane >> 4, l16 = lane & 15;
    const int wm = wave >> 1, wn = wave & 1;
    const int row0 = blockIdx.x * 128;

    // ---- phase 1: h1 = relu(aggx @ W1 + b1) into LDS ----
    bf16x8 a1[4], bw1[4];
#pragma unroll
    for (int t = 0; t < 4; t++) {
        int r = row0 + wm * 64 + t * 16 + l16;
        a1[t] = (r < N) ? *(const bf16x8*)&aggx[(size_t)r * 32 + quad * 8]
                        : (bf16x8)(short)0;
        bw1[t] = *(const bf16x8*)&w1t[(wn * 64 + t * 16 + l16) * 32 + quad * 8];
    }
    // stage Ws chunk c=0 (independent of h1s)
#pragma unroll
    for (int jj = 0; jj < 4; jj++) {
        int idx = tid + jj * 256;
        int r = idx >> 3, ku = idx & 7;
        *(uint4*)&Ws[r * 72 + ku * 8] = *(const uint4*)&wt[(size_t)r * 128 + ku * 8];
    }
    float b1v[4];
#pragma unroll
    for (int tn = 0; tn < 4; tn++) b1v[tn] = b1[wn * 64 + tn * 16 + l16];
#pragma unroll
    for (int tm = 0; tm < 4; tm++) {
#pragma unroll
        for (int tn = 0; tn < 4; tn++) {
            f32x4 hacc = __builtin_amdgcn_mfma_f32_16x16x32_bf16(
                a1[tm], bw1[tn], (f32x4)0.f, 0, 0, 0);
            int rl = wm * 64 + tm * 16 + quad * 4;
            int col = wn * 64 + tn * 16 + l16;
#pragma unroll
            for (int r = 0; r < 4; r++)
                h1s[(rl + r) * 136 + col] = f2bf(fmaxf(hacc[r] + b1v[tn], 0.f));
        }
    }
    __syncthreads();

    // ---- phase 2: K-loop over h1s @ W2 ----
    f32x4 acc[4][4];
#pragma unroll
    for (int i = 0; i < 4; i++)
#pragma unroll
        for (int j = 0; j < 4; j++) acc[i][j] = (f32x4)0.f;

    for (int c = 0; c < 2; c++) {
        if (c == 1) {
            __syncthreads();
#pragma unroll
            for (int jj = 0; jj < 4; jj++) {
                int idx = tid + jj * 256;
                int r = idx >> 3, ku = idx & 7;
                *(uint4*)&Ws[r * 72 + ku * 8] =
                    *(const uint4*)&wt[(size_t)r * 128 + 64 + ku * 8];
            }
            __syncthreads();
        }
#pragma unroll
        for (int kc = 0; kc < 2; kc++) {
            const int klA = c * 64 + kc * 32 + quad * 8;
            const int klW = kc * 32 + quad * 8;
            bf16x8 af[4], bfr[4];
#pragma unroll
            for (int t = 0; t < 4; t++) {
                af[t]  = *(const bf16x8*)&h1s[(wm * 64 + t * 16 + l16) * 136 + klA];
                bfr[t] = *(const bf16x8*)&Ws[(wn * 64 + t * 16 + l16) * 72 + klW];
            }
#pragma unroll
            for (int tm = 0; tm < 4; tm++)
#pragma unroll
                for (int tn = 0; tn < 4; tn++)
                    acc[tm][tn] = __builtin_amdgcn_mfma_f32_16x16x32_bf16(
                        af[tm], bfr[tn], acc[tm][tn], 0, 0, 0);
        }
    }

#pragma unroll
    for (int tm = 0; tm < 4; tm++) {
        const int rbase = row0 + wm * 64 + tm * 16 + quad * 4;
        float dv[4];
#pragma unroll
        for (int r = 0; r < 4; r++)
            dv[r] = (rbase + r < N) ? dis[rbase + r] : 0.f;
#pragma unroll
        for (int tn = 0; tn < 4; tn++) {
            const int col = wn * 64 + tn * 16 + l16;
#pragma unroll
            for (int r = 0; r < 4; r++) {
                if (rbase + r < N)
                    C[(size_t)(rbase + r) * 128 + col] = f2bf(dv[r] * acc[tm][tn][r]);
            }
        }
    }
}

// ---- fused agg128+fc: out = (relu(d*(t2s[dst]+sum w*t2s[src]) + b2)) @ Wfc + bfc ----
// Wave owns 16 nodes; lane (m=lane&15, q=lane>>4) accumulates feats {ks*32+q*8+j}
// in registers == MFMA A-fragment layout. No LDS, no h2 roundtrip.
__global__ __launch_bounds__(256) void aggfc_k(const int* __restrict__ rowptr,
                                               const uint2* __restrict__ meta,
                                               const unsigned short* __restrict__ h,
                                               const float* __restrict__ dis,
                                               const float* __restrict__ b2,
                                               const unsigned short* __restrict__ wfct,
                                               const float* __restrict__ bfc,
                                               float* __restrict__ out, int N) {
    const int tid = threadIdx.x;
    const int wv = tid >> 6, lane = tid & 63;
    const int q = lane >> 4, m = lane & 15;
    const int nbase = blockIdx.x * 64 + wv * 16;
    const int node = nbase + m;
    const bool valid = node < N;

    float acc[4][8];
    if (valid) {
        const uint4* self = (const uint4*)&h[(size_t)node * 128];
#pragma unroll
        for (int ks = 0; ks < 4; ks++) set8(acc[ks], self[ks * 4 + q]);
    } else {
#pragma unroll
        for (int ks = 0; ks < 4; ks++)
#pragma unroll
            for (int jj = 0; jj < 8; jj++) acc[ks][jj] = 0.f;
    }

    int j = valid ? rowptr[node] : 0;
    int jend = valid ? rowptr[node + 1] : 0;
    for (; j + 1 < jend; j += 2) {
        uint2 m0 = meta[j], m1 = meta[j + 1];
        const uint4* s0 = (const uint4*)&h[(size_t)m0.x * 128];
        const uint4* s1 = (const uint4*)&h[(size_t)m1.x * 128];
        uint4 g0[4], g1[4];
#pragma unroll
        for (int ks = 0; ks < 4; ks++) { g0[ks] = s0[ks * 4 + q]; g1[ks] = s1[ks * 4 + q]; }
        float w0 = __uint_as_float(m0.y), w1 = __uint_as_float(m1.y);
#pragma unroll
        for (int ks = 0; ks < 4; ks++) { fma8(acc[ks], w0, g0[ks]); fma8(acc[ks], w1, g1[ks]); }
    }
    if (j < jend) {
        uint2 mt = meta[j];
        const uint4* s0 = (const uint4*)&h[(size_t)mt.x * 128];
        float w0 = __uint_as_float(mt.y);
#pragma unroll
        for (int ks = 0; ks < 4; ks++) fma8(acc[ks], w0, s0[ks * 4 + q]);
    }

    // epilogue: h2 = relu(d*acc + b2) -> A-frags (in register)
    float d = valid ? dis[node] : 0.f;
    bf16x8 af[4];
#pragma unroll
    for (int ks = 0; ks < 4; ks++) {
        const float4* bp = (const float4*)&b2[ks * 32 + q * 8];
        float4 bA = bp[0], bB = bp[1];
        union { bf16x8 v; unsigned short s[8]; } u;
        u.s[0] = f2bf(fmaxf(fmaf(d, acc[ks][0], bA.x), 0.f));
        u.s[1] = f2bf(fmaxf(fmaf(d, acc[ks][1], bA.y), 0.f));
        u.s[2] = f2bf(fmaxf(fmaf(d, acc[ks][2], bA.z), 0.f));
        u.s[3] = f2bf(fmaxf(fmaf(d, acc[ks][3], bA.w), 0.f));
        u.s[4] = f2bf(fmaxf(fmaf(d, acc[ks][4], bB.x), 0.f));
        u.s[5] = f2bf(fmaxf(fmaf(d, acc[ks][5], bB.y), 0.f));
        u.s[6] = f2bf(fmaxf(fmaf(d, acc[ks][6], bB.z), 0.f));
        u.s[7] = f2bf(fmaxf(fmaf(d, acc[ks][7], bB.w), 0.f));
        af[ks] = u.v;
    }

    // fc: 2 col-tiles x 4 K-steps
#pragma unroll
    for (int n = 0; n < 2; n++) {
        f32x4 o = (f32x4)0.f;
#pragma unroll
        for (int ks = 0; ks < 4; ks++) {
            bf16x8 bfr = *(const bf16x8*)&wfct[(size_t)(n * 16 + m) * 128 + ks * 32 + q * 8];
            o = __builtin_amdgcn_mfma_f32_16x16x32_bf16(af[ks], bfr, o, 0, 0, 0);
        }
        int col = n * 16 + m;
        if (col < NCLASS) {
            float bv = bfc[col];
            int r0 = nbase + q * 4;
#pragma unroll
            for (int r = 0; r < 4; r++) {
                if (r0 + r < N)
                    out[(size_t)(r0 + r) * NCLASS + col] = o[r] + bv;
            }
        }
    }
}

extern "C" void kernel_launch(void* const* d_in, const int* in_sizes, int n_in,
                              void* d_out, int out_size, void* d_ws, size_t ws_size,
                              hipStream_t stream) {
    const float* x   = (const float*)d_in[0];
    const int*   ei  = (const int*)d_in[1];
    const float* ew  = (const float*)d_in[2];
    const float* W1  = (const float*)d_in[3];
    const float* b1  = (const float*)d_in[4];
    const float* W2  = (const float*)d_in[5];
    const float* b2  = (const float*)d_in[6];
    const float* Wfc = (const float*)d_in[7];
    const float* bfc = (const float*)d_in[8];
    float* out = (float*)d_out;

    const int N = NNODES;
    const int* erow = ei;
    const int* ecol = ei + NEDGES;

    // ws layout (float-unit offsets):
    float* fws    = (float*)d_ws;
    float* dis    = fws;                                       // 100000
    int*   rowptr = (int*)(fws + 100000);                      // 100001 (+pad)
    int*   H      = (int*)(fws + 200004);                      // 114856
    int*   incl   = (int*)(fws + 314860);                      // 114856
    int*   aux    = (int*)(fws + 429716);                      // 512
    uint2* rw     = (uint2*)(fws + 430228);                    // 600000 uint2
    unsigned short* lc = (unsigned short*)(fws + 1630228);     // 600000 u16
    uint2* meta   = (uint2*)(fws + 1930228);                   // 600000 uint2
    unsigned short* wt16   = (unsigned short*)(fws + 3130228); // 128*128
    unsigned short* w1t16  = (unsigned short*)(fws + 3138420); // 128*32
    unsigned short* wfct16 = (unsigned short*)(fws + 3140468); // 32*128
    unsigned int*   xp     = (unsigned int*)(fws + 3142516);   // N*16
    unsigned int*   aggx   = (unsigned int*)(fws + 4742516);   // N*16
    unsigned short* hB16   = (unsigned short*)(fws + 6342516); // N*128 bf16 (t2s)

    const int gScan = (NH + 255) / 256;   // 449
    const int g128  = (N + 127) / 128;    // 782
    const int gA26  = N / 16;             // 6250
    const int gPrep = 96 + (N * 16 + 255) / 256;
    const int gFc   = (N + 63) / 64;      // 1563

    // ---- CSR build (5 kernels) ----
    histA_k<<<NBE, 256, 0, stream>>>(ecol, H);
    scanH1_k<<<gScan, 256, 0, stream>>>(H, incl, aux, NH);
    scan2_k<<<1, 512, 0, stream>>>(aux, gScan);
    partB_k<<<NBE, 256, 0, stream>>>(erow, ecol, ew, incl, H, aux, rw, lc);
    segbp_k<<<NBKT, 256, 0, stream>>>(rw, lc, incl, H, aux, rowptr, dis, meta);

    // ---- prep ----
    prep_k<<<gPrep, 256, 0, stream>>>(W2, W1, Wfc, x, dis, wt16, w1t16, wfct16, xp);

    // ---- layer 1 agg -> fused gemm1+gemm2 ----
    agg26_k<<<gA26, 256, 0, stream>>>(rowptr, meta, xp, dis, aggx);
    gemm12_k<<<g128, 256, 0, stream>>>((const unsigned short*)aggx, w1t16, b1,
                                       wt16, dis, hB16, N);

    // ---- fused agg128 + fc ----
    aggfc_k<<<gFc, 256, 0, stream>>>(rowptr, meta, hB16, dis, b2, wfct16, bfc, out, N);
}